// Round 1
// baseline (1819.964 us; speedup 1.0000x reference)
//
#include <hip/hip_runtime.h>

#define N_NODES  100000
#define N_EDGES  1600000
#define DIM      64
#define N_GRAPHS 128
#define OUT_DIM  10

// ---------------- CSR build (bucket edges by dst) ----------------

__global__ void count_kernel(const int* __restrict__ dst, int* __restrict__ counts, int n) {
    int i = blockIdx.x * blockDim.x + threadIdx.x;
    int stride = gridDim.x * blockDim.x;
    for (; i < n; i += stride) atomicAdd(&counts[dst[i]], 1);
}

__global__ void scan_kernel(const int* __restrict__ counts, int* __restrict__ row_ptr, int n) {
    __shared__ int sums[1024];
    const int tid = threadIdx.x;
    const int chunk = (n + 1023) >> 10;
    const int beg = tid * chunk;
    const int end_ = min(beg + chunk, n);
    int s = 0;
    for (int i = beg; i < end_; ++i) s += counts[i];
    sums[tid] = s;
    __syncthreads();
    for (int off = 1; off < 1024; off <<= 1) {
        int v = (tid >= off) ? sums[tid - off] : 0;
        __syncthreads();
        sums[tid] += v;
        __syncthreads();
    }
    int running = sums[tid] - s;  // exclusive prefix
    for (int i = beg; i < end_; ++i) { row_ptr[i] = running; running += counts[i]; }
    if (tid == 1023) row_ptr[n] = sums[1023];
}

__global__ void fill_kernel(const int* __restrict__ src, const int* __restrict__ dst,
                            const int* __restrict__ row_ptr, int* __restrict__ fillc,
                            int* __restrict__ col_idx, int n) {
    int i = blockIdx.x * blockDim.x + threadIdx.x;
    int stride = gridDim.x * blockDim.x;
    for (; i < n; i += stride) {
        int d = dst[i];
        int pos = row_ptr[d] + atomicAdd(&fillc[d], 1);
        col_idx[pos] = src[i];
    }
}

// ---------------- Fused GIN layer: agg + MLP(BN,ReLU) ----------------
// Wave per node; lane = feature dim. Weight columns live in VGPRs (128 regs),
// activation broadcast via LDS float4 reads (same-address broadcast = free).

__global__ void gin_layer_kernel(
    const float* __restrict__ h_in, float* __restrict__ h_out,
    const int* __restrict__ row_ptr, const int* __restrict__ col_idx,
    const float* __restrict__ W1, const float* __restrict__ b1,
    const float* __restrict__ gamma, const float* __restrict__ beta,
    const float* __restrict__ rmean, const float* __restrict__ rvar,
    const float* __restrict__ W2, const float* __restrict__ b2, int n)
{
    __shared__ __align__(16) float t_lds[4][DIM];
    const int lane = threadIdx.x & 63;
    const int wid  = threadIdx.x >> 6;

    // per-lane weight columns: w1c[d] = W1[d][lane]
    float w1c[DIM], w2c[DIM];
#pragma unroll
    for (int d = 0; d < DIM; ++d) w1c[d] = W1[d * DIM + lane];
#pragma unroll
    for (int d = 0; d < DIM; ++d) w2c[d] = W2[d * DIM + lane];
    const float b1v = b1[lane], b2v = b2[lane];
    const float scale = gamma[lane] * rsqrtf(rvar[lane] + 1e-5f);
    const float shift = beta[lane] - rmean[lane] * scale;

    const int wave   = blockIdx.x * 4 + wid;
    const int nwaves = gridDim.x * 4;
    for (int i = wave; i < n; i += nwaves) {
        const int start = row_ptr[i];
        const int end   = row_ptr[i + 1];
        float acc = h_in[i * DIM + lane];  // self term (eps = 0)
        for (int e0 = start; e0 < end; e0 += 64) {
            const int navail = end - e0;
            int myidx = 0;
            if (lane < navail) myidx = col_idx[e0 + lane];  // whole neighborhood in 1 load
            const int cnt = min(64, navail);
            int j = 0;
            for (; j + 4 <= cnt; j += 4) {  // 4 gathers in flight
                int s0 = __shfl(myidx, j);
                int s1 = __shfl(myidx, j + 1);
                int s2 = __shfl(myidx, j + 2);
                int s3 = __shfl(myidx, j + 3);
                float v0 = h_in[s0 * DIM + lane];
                float v1 = h_in[s1 * DIM + lane];
                float v2 = h_in[s2 * DIM + lane];
                float v3 = h_in[s3 * DIM + lane];
                acc += (v0 + v1) + (v2 + v3);
            }
            for (; j < cnt; ++j) {
                int s = __shfl(myidx, j);
                acc += h_in[s * DIM + lane];
            }
        }
        // t = h_i + agg  -> LDS for cross-lane broadcast (wave-synchronous)
        t_lds[wid][lane] = acc;
        float y = b1v;
#pragma unroll
        for (int d = 0; d < DIM; d += 4) {
            float4 t4 = *reinterpret_cast<const float4*>(&t_lds[wid][d]);
            y += t4.x * w1c[d] + t4.y * w1c[d + 1] + t4.z * w1c[d + 2] + t4.w * w1c[d + 3];
        }
        float u = fmaxf(y * scale + shift, 0.0f);  // BN(eval) + ReLU
        t_lds[wid][lane] = u;
        float y2 = b2v;
#pragma unroll
        for (int d = 0; d < DIM; d += 4) {
            float4 u4 = *reinterpret_cast<const float4*>(&t_lds[wid][d]);
            y2 += u4.x * w2c[d] + u4.y * w2c[d + 1] + u4.z * w2c[d + 2] + u4.w * w2c[d + 3];
        }
        h_out[i * DIM + lane] = fmaxf(y2, 0.0f);
    }
}

// ---------------- global_add_pool (batch is sorted -> run-length + atomics) --------

__global__ void pool_kernel(const float* __restrict__ h, const int* __restrict__ batch,
                            float* __restrict__ pooled, int n) {
    const int lane = threadIdx.x & 63;
    const int wid  = threadIdx.x >> 6;
    const int wave = blockIdx.x * 4 + wid;
    const int nwaves = gridDim.x * 4;
    const int per = (n + nwaves - 1) / nwaves;
    const int a = wave * per;
    const int b = min(a + per, n);
    if (a >= b) return;
    int cur = batch[a];
    float sum = 0.0f;
    for (int i = a; i < b; ++i) {
        int g = batch[i];
        if (g != cur) {
            atomicAdd(&pooled[cur * DIM + lane], sum);
            sum = 0.0f;
            cur = g;
        }
        sum += h[i * DIM + lane];
    }
    atomicAdd(&pooled[cur * DIM + lane], sum);
}

// ---------------- head: relu(pooled@lin1+b1) @ lin2 + b2 ----------------

__global__ void head_kernel(const float* __restrict__ pooled,
                            const float* __restrict__ w1, const float* __restrict__ b1,
                            const float* __restrict__ w2, const float* __restrict__ b2,
                            float* __restrict__ out) {
    const int g = blockIdx.x;
    const int lane = threadIdx.x;  // 64 threads = 1 wave
    __shared__ float pl[DIM];
    __shared__ float y1l[DIM];
    pl[lane] = pooled[g * DIM + lane];
    __syncthreads();
    float y = b1[lane];
#pragma unroll
    for (int d = 0; d < DIM; ++d) y += pl[d] * w1[d * DIM + lane];
    y1l[lane] = fmaxf(y, 0.0f);
    __syncthreads();
    if (lane < OUT_DIM) {
        float y2 = b2[lane];
#pragma unroll
        for (int d = 0; d < DIM; ++d) y2 += y1l[d] * w2[d * OUT_DIM + lane];
        out[g * OUT_DIM + lane] = y2;
    }
}

// ---------------- launch ----------------

extern "C" void kernel_launch(void* const* d_in, const int* in_sizes, int n_in,
                              void* d_out, int out_size, void* d_ws, size_t ws_size,
                              hipStream_t stream) {
    const float* x     = (const float*)d_in[0];
    const int*   eidx  = (const int*)  d_in[1];   // [2, N_EDGES]: src row then dst row
    const int*   batch = (const int*)  d_in[2];
    const float* W1    = (const float*)d_in[3];
    const float* b1    = (const float*)d_in[4];
    const float* gamma = (const float*)d_in[5];
    const float* beta  = (const float*)d_in[6];
    const float* rmean = (const float*)d_in[7];
    const float* rvar  = (const float*)d_in[8];
    const float* W2    = (const float*)d_in[9];
    const float* b2    = (const float*)d_in[10];
    const float* l1w   = (const float*)d_in[11];
    const float* l1b   = (const float*)d_in[12];
    const float* l2w   = (const float*)d_in[13];
    const float* l2b   = (const float*)d_in[14];
    float* out = (float*)d_out;

    // workspace layout (int-element offsets, padded to keep 16B alignment)
    int* counts  = (int*)d_ws;            // 100000
    int* fillc   = counts  + 100352;      // 100000
    int* row_ptr = fillc   + 100352;      // 100001
    int* col_idx = row_ptr + 100352;      // 1600000
    float* hA    = (float*)(col_idx + 1600000 + 192);
    float* hB    = hA + (size_t)N_NODES * DIM;
    float* pooled = hB + (size_t)N_NODES * DIM;

    const int* srcp = eidx;
    const int* dstp = eidx + N_EDGES;

    hipMemsetAsync(counts, 0, N_NODES * sizeof(int), stream);
    hipMemsetAsync(fillc,  0, N_NODES * sizeof(int), stream);
    hipMemsetAsync(pooled, 0, N_GRAPHS * DIM * sizeof(float), stream);

    count_kernel<<<512, 256, 0, stream>>>(dstp, counts, N_EDGES);
    scan_kernel<<<1, 1024, 0, stream>>>(counts, row_ptr, N_NODES);
    fill_kernel<<<512, 256, 0, stream>>>(srcp, dstp, row_ptr, fillc, col_idx, N_EDGES);

    const float* hin = x;
    float* houts[5] = {hA, hB, hA, hB, hA};
    for (int l = 0; l < 5; ++l) {
        gin_layer_kernel<<<1024, 256, 0, stream>>>(
            hin, houts[l], row_ptr, col_idx,
            W1 + (size_t)l * DIM * DIM, b1 + (size_t)l * DIM,
            gamma + (size_t)l * DIM, beta + (size_t)l * DIM,
            rmean + (size_t)l * DIM, rvar + (size_t)l * DIM,
            W2 + (size_t)l * DIM * DIM, b2 + (size_t)l * DIM, N_NODES);
        hin = houts[l];
    }
    pool_kernel<<<1024, 256, 0, stream>>>(hA, batch, pooled, N_NODES);
    head_kernel<<<N_GRAPHS, 64, 0, stream>>>(pooled, l1w, l1b, l2w, l2b, out);
}

// Round 2
// 1154.629 us; speedup vs baseline: 1.5762x; 1.5762x over previous
//
#include <hip/hip_runtime.h>

#define N_NODES  100000
#define N_EDGES  1600000
#define DIM      64
#define N_GRAPHS 128
#define OUT_DIM  10

// ---------------- CSR build (bucket edges by dst) ----------------

__global__ void count_kernel(const int* __restrict__ dst, int* __restrict__ counts, int n) {
    int i = blockIdx.x * blockDim.x + threadIdx.x;
    int stride = gridDim.x * blockDim.x;
    for (; i < n; i += stride) atomicAdd(&counts[dst[i]], 1);
}

__global__ void scan_kernel(const int* __restrict__ counts, int* __restrict__ row_ptr, int n) {
    __shared__ int sums[1024];
    const int tid = threadIdx.x;
    const int chunk = (n + 1023) >> 10;
    const int beg = tid * chunk;
    const int end_ = min(beg + chunk, n);
    int s = 0;
    for (int i = beg; i < end_; ++i) s += counts[i];
    sums[tid] = s;
    __syncthreads();
    for (int off = 1; off < 1024; off <<= 1) {
        int v = (tid >= off) ? sums[tid - off] : 0;
        __syncthreads();
        sums[tid] += v;
        __syncthreads();
    }
    int running = sums[tid] - s;  // exclusive prefix
    for (int i = beg; i < end_; ++i) { row_ptr[i] = running; running += counts[i]; }
    if (tid == 1023) row_ptr[n] = sums[1023];
}

__global__ void fill_kernel(const int* __restrict__ src, const int* __restrict__ dst,
                            const int* __restrict__ row_ptr, int* __restrict__ fillc,
                            int* __restrict__ col_idx, int n) {
    int i = blockIdx.x * blockDim.x + threadIdx.x;
    int stride = gridDim.x * blockDim.x;
    for (; i < n; i += stride) {
        int d = dst[i];
        int pos = row_ptr[d] + atomicAdd(&fillc[d], 1);
        col_idx[pos] = src[i];
    }
}

// ---------------- Aggregation: t[i] = h[i] + sum_{j in N(i)} h[j] ----------------
// One wave per node. Lane = feature dim -> each gather is one coalesced 256B row.
// 8 loads in flight; low VGPR so occupancy is maximal; 100K waves for latency hiding.

__global__ __launch_bounds__(256) void agg_kernel(
    const float* __restrict__ h, float* __restrict__ t,
    const int* __restrict__ row_ptr, const int* __restrict__ col_idx, int n)
{
    const int lane = threadIdx.x & 63;
    const int wave = (blockIdx.x * blockDim.x + threadIdx.x) >> 6;
    if (wave >= n) return;
    const int i = wave;
    const int start = row_ptr[i];
    const int end   = row_ptr[i + 1];
    float acc = h[(size_t)i * DIM + lane];  // self term (eps = 0)
    for (int e0 = start; e0 < end; e0 += 64) {
        const int navail = end - e0;
        int myidx = (lane < navail) ? col_idx[e0 + lane] : 0;
        const int cnt = min(64, navail);
        int j = 0;
        for (; j + 8 <= cnt; j += 8) {  // 8 gathers in flight
            int s0 = __shfl(myidx, j + 0), s1 = __shfl(myidx, j + 1);
            int s2 = __shfl(myidx, j + 2), s3 = __shfl(myidx, j + 3);
            int s4 = __shfl(myidx, j + 4), s5 = __shfl(myidx, j + 5);
            int s6 = __shfl(myidx, j + 6), s7 = __shfl(myidx, j + 7);
            float v0 = h[(size_t)s0 * DIM + lane], v1 = h[(size_t)s1 * DIM + lane];
            float v2 = h[(size_t)s2 * DIM + lane], v3 = h[(size_t)s3 * DIM + lane];
            float v4 = h[(size_t)s4 * DIM + lane], v5 = h[(size_t)s5 * DIM + lane];
            float v6 = h[(size_t)s6 * DIM + lane], v7 = h[(size_t)s7 * DIM + lane];
            acc += ((v0 + v1) + (v2 + v3)) + ((v4 + v5) + (v6 + v7));
        }
        for (; j < cnt; ++j) {
            int s = __shfl(myidx, j);
            acc += h[(size_t)s * DIM + lane];
        }
    }
    t[(size_t)i * DIM + lane] = acc;
}

// ---------------- MLP: h_out = relu( relu(BN(t@W1+b1)) @ W2 + b2 ) ----------------
// Wave per node, lane = output dim. Weight COLUMNS live in explicit float4 VGPR
// arrays (128 VGPRs), loaded once per wave and amortized over ~32 nodes.
// Activation broadcast via LDS float4 reads (same-address broadcast = free).

__global__ __launch_bounds__(256) void mlp_kernel(
    const float* __restrict__ t, float* __restrict__ h_out,
    const float* __restrict__ W1, const float* __restrict__ b1,
    const float* __restrict__ gamma, const float* __restrict__ beta,
    const float* __restrict__ rmean, const float* __restrict__ rvar,
    const float* __restrict__ W2, const float* __restrict__ b2, int n)
{
    __shared__ __align__(16) float t_lds[4][DIM];
    const int lane = threadIdx.x & 63;
    const int wid  = threadIdx.x >> 6;

    float4 w1v[16], w2v[16];
#pragma unroll
    for (int d4 = 0; d4 < 16; ++d4) {
        w1v[d4] = make_float4(W1[(4 * d4 + 0) * DIM + lane], W1[(4 * d4 + 1) * DIM + lane],
                              W1[(4 * d4 + 2) * DIM + lane], W1[(4 * d4 + 3) * DIM + lane]);
        w2v[d4] = make_float4(W2[(4 * d4 + 0) * DIM + lane], W2[(4 * d4 + 1) * DIM + lane],
                              W2[(4 * d4 + 2) * DIM + lane], W2[(4 * d4 + 3) * DIM + lane]);
    }
    const float b1v = b1[lane], b2v = b2[lane];
    const float scale = gamma[lane] * rsqrtf(rvar[lane] + 1e-5f);
    const float shift = beta[lane] - rmean[lane] * scale;

    const int wave   = blockIdx.x * 4 + wid;
    const int nwaves = gridDim.x * 4;
    for (int i = wave; i < n; i += nwaves) {
        t_lds[wid][lane] = t[(size_t)i * DIM + lane];
        float y = b1v;
#pragma unroll
        for (int d4 = 0; d4 < 16; ++d4) {
            float4 t4 = *reinterpret_cast<const float4*>(&t_lds[wid][4 * d4]);
            y += t4.x * w1v[d4].x + t4.y * w1v[d4].y + t4.z * w1v[d4].z + t4.w * w1v[d4].w;
        }
        float u = fmaxf(y * scale + shift, 0.0f);  // BN(eval) + ReLU
        t_lds[wid][lane] = u;
        float y2 = b2v;
#pragma unroll
        for (int d4 = 0; d4 < 16; ++d4) {
            float4 u4 = *reinterpret_cast<const float4*>(&t_lds[wid][4 * d4]);
            y2 += u4.x * w2v[d4].x + u4.y * w2v[d4].y + u4.z * w2v[d4].z + u4.w * w2v[d4].w;
        }
        h_out[(size_t)i * DIM + lane] = fmaxf(y2, 0.0f);
    }
}

// ---------------- global_add_pool (batch sorted -> run-length + atomics) --------

__global__ void pool_kernel(const float* __restrict__ h, const int* __restrict__ batch,
                            float* __restrict__ pooled, int n) {
    const int lane = threadIdx.x & 63;
    const int wid  = threadIdx.x >> 6;
    const int wave = blockIdx.x * 4 + wid;
    const int nwaves = gridDim.x * 4;
    const int per = (n + nwaves - 1) / nwaves;
    const int a = wave * per;
    const int b = min(a + per, n);
    if (a >= b) return;
    int cur = batch[a];
    float sum = 0.0f;
    for (int i = a; i < b; ++i) {
        int g = batch[i];
        if (g != cur) {
            atomicAdd(&pooled[cur * DIM + lane], sum);
            sum = 0.0f;
            cur = g;
        }
        sum += h[(size_t)i * DIM + lane];
    }
    atomicAdd(&pooled[cur * DIM + lane], sum);
}

// ---------------- head: relu(pooled@lin1+b1) @ lin2 + b2 ----------------

__global__ void head_kernel(const float* __restrict__ pooled,
                            const float* __restrict__ w1, const float* __restrict__ b1,
                            const float* __restrict__ w2, const float* __restrict__ b2,
                            float* __restrict__ out) {
    const int g = blockIdx.x;
    const int lane = threadIdx.x;  // 64 threads = 1 wave
    __shared__ float pl[DIM];
    __shared__ float y1l[DIM];
    pl[lane] = pooled[g * DIM + lane];
    __syncthreads();
    float y = b1[lane];
#pragma unroll
    for (int d = 0; d < DIM; ++d) y += pl[d] * w1[d * DIM + lane];
    y1l[lane] = fmaxf(y, 0.0f);
    __syncthreads();
    if (lane < OUT_DIM) {
        float y2 = b2[lane];
#pragma unroll
        for (int d = 0; d < DIM; ++d) y2 += y1l[d] * w2[d * OUT_DIM + lane];
        out[g * OUT_DIM + lane] = y2;
    }
}

// ---------------- launch ----------------

extern "C" void kernel_launch(void* const* d_in, const int* in_sizes, int n_in,
                              void* d_out, int out_size, void* d_ws, size_t ws_size,
                              hipStream_t stream) {
    const float* x     = (const float*)d_in[0];
    const int*   eidx  = (const int*)  d_in[1];   // [2, N_EDGES]: src row then dst row
    const int*   batch = (const int*)  d_in[2];
    const float* W1    = (const float*)d_in[3];
    const float* b1    = (const float*)d_in[4];
    const float* gamma = (const float*)d_in[5];
    const float* beta  = (const float*)d_in[6];
    const float* rmean = (const float*)d_in[7];
    const float* rvar  = (const float*)d_in[8];
    const float* W2    = (const float*)d_in[9];
    const float* b2    = (const float*)d_in[10];
    const float* l1w   = (const float*)d_in[11];
    const float* l1b   = (const float*)d_in[12];
    const float* l2w   = (const float*)d_in[13];
    const float* l2b   = (const float*)d_in[14];
    float* out = (float*)d_out;

    // workspace layout (padded to keep 16B alignment)
    int* counts  = (int*)d_ws;            // 100000
    int* fillc   = counts  + 100352;      // 100000
    int* row_ptr = fillc   + 100352;      // 100001
    int* col_idx = row_ptr + 100352;      // 1600000
    float* bufA  = (float*)(col_idx + 1600000 + 192);        // 100000*64
    float* bufB  = bufA + (size_t)N_NODES * DIM;
    float* bufC  = bufB + (size_t)N_NODES * DIM;
    float* pooled = bufC + (size_t)N_NODES * DIM;

    const int* srcp = eidx;
    const int* dstp = eidx + N_EDGES;

    hipMemsetAsync(counts, 0, N_NODES * sizeof(int), stream);
    hipMemsetAsync(fillc,  0, N_NODES * sizeof(int), stream);
    hipMemsetAsync(pooled, 0, N_GRAPHS * DIM * sizeof(float), stream);

    count_kernel<<<1024, 256, 0, stream>>>(dstp, counts, N_EDGES);
    scan_kernel<<<1, 1024, 0, stream>>>(counts, row_ptr, N_NODES);
    fill_kernel<<<1024, 256, 0, stream>>>(srcp, dstp, row_ptr, fillc, col_idx, N_EDGES);

    const int agg_blocks = (N_NODES * 64 + 255) / 256;  // one wave per node
    const int mlp_blocks = 782;                          // ~32 nodes per wave

    // buffer rotation: layer inputs/outputs never alias t
    const float* hin = x;
    float* tbuf;
    float* hout;
    float* houts[5];
    // L1: in=x   t=A out=B ; L2: in=B t=A out=C ; L3: in=C t=A out=B ;
    // L4: in=B   t=A out=C ; L5: in=C t=A out=B
    float* outs[5] = {bufB, bufC, bufB, bufC, bufB};
    for (int l = 0; l < 5; ++l) {
        tbuf = bufA;
        hout = outs[l];
        agg_kernel<<<agg_blocks, 256, 0, stream>>>(hin, tbuf, row_ptr, col_idx, N_NODES);
        mlp_kernel<<<mlp_blocks, 256, 0, stream>>>(
            tbuf, hout,
            W1 + (size_t)l * DIM * DIM, b1 + (size_t)l * DIM,
            gamma + (size_t)l * DIM, beta + (size_t)l * DIM,
            rmean + (size_t)l * DIM, rvar + (size_t)l * DIM,
            W2 + (size_t)l * DIM * DIM, b2 + (size_t)l * DIM, N_NODES);
        hin = hout;
        houts[l] = hout;
    }
    pool_kernel<<<2048, 256, 0, stream>>>(houts[4], batch, pooled, N_NODES);
    head_kernel<<<N_GRAPHS, 64, 0, stream>>>(pooled, l1w, l1b, l2w, l2b, out);
}

// Round 3
// 973.535 us; speedup vs baseline: 1.8694x; 1.1860x over previous
//
#include <hip/hip_runtime.h>

#define N_NODES  100000
#define N_EDGES  1600000
#define DIM      64
#define N_GRAPHS 128
#define OUT_DIM  10
#define SCAN_NB    196
#define SCAN_CHUNK 512   // 196*512 = 100352 >= N_NODES; 2 elems/thread @256 threads

// ---------------- CSR build (bucket edges by dst) ----------------

__global__ void count_kernel(const int* __restrict__ dst, int* __restrict__ counts, int n) {
    int i = blockIdx.x * blockDim.x + threadIdx.x;
    int stride = gridDim.x * blockDim.x;
    for (; i < n; i += stride) atomicAdd(&counts[dst[i]], 1);
}

// 3-phase multi-block exclusive scan of counts -> row_ptr
__global__ void scanA_kernel(const int* __restrict__ counts, int* __restrict__ blockSums, int n) {
    __shared__ int red[256];
    const int b = blockIdx.x, t = threadIdx.x;
    const int base = b * SCAN_CHUNK + t * 2;
    int s = 0;
    if (base < n)     s += counts[base];
    if (base + 1 < n) s += counts[base + 1];
    red[t] = s;
    __syncthreads();
    for (int off = 128; off > 0; off >>= 1) {
        if (t < off) red[t] += red[t + off];
        __syncthreads();
    }
    if (t == 0) blockSums[b] = red[0];
}

__global__ void scanB_kernel(const int* __restrict__ blockSums, int* __restrict__ blockOffs,
                             int* __restrict__ row_ptr) {
    __shared__ int sc[256];
    const int t = threadIdx.x;
    const int v = (t < SCAN_NB) ? blockSums[t] : 0;
    sc[t] = v;
    __syncthreads();
    for (int off = 1; off < 256; off <<= 1) {
        int u = (t >= off) ? sc[t - off] : 0;
        __syncthreads();
        sc[t] += u;
        __syncthreads();
    }
    if (t < SCAN_NB) blockOffs[t] = sc[t] - v;   // exclusive block offset
    if (t == 255) row_ptr[N_NODES] = sc[255];    // total == N_EDGES
}

__global__ void scanC_kernel(const int* __restrict__ counts, const int* __restrict__ blockOffs,
                             int* __restrict__ row_ptr, int n) {
    __shared__ int sc[256];
    const int b = blockIdx.x, t = threadIdx.x;
    const int base = b * SCAN_CHUNK + t * 2;
    const int c0 = (base < n) ? counts[base] : 0;
    const int c1 = (base + 1 < n) ? counts[base + 1] : 0;
    const int s = c0 + c1;
    sc[t] = s;
    __syncthreads();
    for (int off = 1; off < 256; off <<= 1) {
        int u = (t >= off) ? sc[t - off] : 0;
        __syncthreads();
        sc[t] += u;
        __syncthreads();
    }
    const int pre = blockOffs[b] + sc[t] - s;    // exclusive prefix for base
    if (base < n)     row_ptr[base]     = pre;
    if (base + 1 < n) row_ptr[base + 1] = pre + c0;
}

__global__ void fill_kernel(const int* __restrict__ src, const int* __restrict__ dst,
                            const int* __restrict__ row_ptr, int* __restrict__ fillc,
                            int* __restrict__ col_idx, int n) {
    int i = blockIdx.x * blockDim.x + threadIdx.x;
    int stride = gridDim.x * blockDim.x;
    for (; i < n; i += stride) {
        int d = dst[i];
        int pos = row_ptr[d] + atomicAdd(&fillc[d], 1);
        col_idx[pos] = src[i];
    }
}

// ---------------- Aggregation: t[i] = h[i] + sum_{j in N(i)} h[j] ----------------
// One wave per node. Lane = (r,q): r = row-slot (4 rows per VMEM instruction via
// dwordx4), q = float4 chunk within row. 4 group-loads unrolled -> 16 rows in
// flight per wave. Tail via mask-predicated group loads (no serial remainder).

__global__ __launch_bounds__(256) void agg_kernel(
    const float* __restrict__ h, float* __restrict__ t,
    const int* __restrict__ row_ptr, const int* __restrict__ col_idx, int n)
{
    const float4* __restrict__ h4 = (const float4*)h;
    float4* __restrict__ t4 = (float4*)t;
    const int lane = threadIdx.x & 63;
    const int r = lane >> 4;     // which of 4 rows this lane loads
    const int q = lane & 15;     // float4 index within the row
    const int i = (blockIdx.x * blockDim.x + threadIdx.x) >> 6;
    if (i >= n) return;
    const int start = row_ptr[i];
    const int end   = row_ptr[i + 1];

    float4 acc = make_float4(0.f, 0.f, 0.f, 0.f);
    for (int e0 = start; e0 < end; e0 += 64) {
        const int navail = end - e0;
        const int cnt = min(64, navail);
        int myidx = (lane < navail) ? col_idx[e0 + lane] : 0;
        int g = 0;
        for (; g + 16 <= cnt; g += 16) {   // 16 rows, 4 dwordx4 gathers in flight
            int s0 = __shfl(myidx, g + r);
            int s1 = __shfl(myidx, g + r + 4);
            int s2 = __shfl(myidx, g + r + 8);
            int s3 = __shfl(myidx, g + r + 12);
            float4 v0 = h4[(size_t)s0 * 16 + q];
            float4 v1 = h4[(size_t)s1 * 16 + q];
            float4 v2 = h4[(size_t)s2 * 16 + q];
            float4 v3 = h4[(size_t)s3 * 16 + q];
            acc.x += (v0.x + v1.x) + (v2.x + v3.x);
            acc.y += (v0.y + v1.y) + (v2.y + v3.y);
            acc.z += (v0.z + v1.z) + (v2.z + v3.z);
            acc.w += (v0.w + v1.w) + (v2.w + v3.w);
        }
        if (g < cnt) {  // masked tail: up to 4 group loads, predicated per r-slot
#pragma unroll
            for (int k = 0; k < 4; ++k) {
                int row = g + 4 * k + r;
                bool valid = row < cnt;
                int sk = __shfl(myidx, valid ? row : 0);
                float4 v = h4[(size_t)sk * 16 + q];
                if (valid) { acc.x += v.x; acc.y += v.y; acc.z += v.z; acc.w += v.w; }
            }
        }
    }
    // reduce across the 4 r-slots (lanes differing in bits 4,5)
    acc.x += __shfl_xor(acc.x, 16); acc.y += __shfl_xor(acc.y, 16);
    acc.z += __shfl_xor(acc.z, 16); acc.w += __shfl_xor(acc.w, 16);
    acc.x += __shfl_xor(acc.x, 32); acc.y += __shfl_xor(acc.y, 32);
    acc.z += __shfl_xor(acc.z, 32); acc.w += __shfl_xor(acc.w, 32);
    if (lane < 16) {
        float4 self = h4[(size_t)i * 16 + q];   // self term (eps = 0)
        acc.x += self.x; acc.y += self.y; acc.z += self.z; acc.w += self.w;
        t4[(size_t)i * 16 + q] = acc;
    }
}

// ---------------- MLP: h_out = relu( relu(BN(t@W1+b1)) @ W2 + b2 ) ----------------

__global__ __launch_bounds__(256) void mlp_kernel(
    const float* __restrict__ t, float* __restrict__ h_out,
    const float* __restrict__ W1, const float* __restrict__ b1,
    const float* __restrict__ gamma, const float* __restrict__ beta,
    const float* __restrict__ rmean, const float* __restrict__ rvar,
    const float* __restrict__ W2, const float* __restrict__ b2, int n)
{
    __shared__ __align__(16) float t_lds[4][DIM];
    const int lane = threadIdx.x & 63;
    const int wid  = threadIdx.x >> 6;

    float4 w1v[16], w2v[16];
#pragma unroll
    for (int d4 = 0; d4 < 16; ++d4) {
        w1v[d4] = make_float4(W1[(4 * d4 + 0) * DIM + lane], W1[(4 * d4 + 1) * DIM + lane],
                              W1[(4 * d4 + 2) * DIM + lane], W1[(4 * d4 + 3) * DIM + lane]);
        w2v[d4] = make_float4(W2[(4 * d4 + 0) * DIM + lane], W2[(4 * d4 + 1) * DIM + lane],
                              W2[(4 * d4 + 2) * DIM + lane], W2[(4 * d4 + 3) * DIM + lane]);
    }
    const float b1v = b1[lane], b2v = b2[lane];
    const float scale = gamma[lane] * rsqrtf(rvar[lane] + 1e-5f);
    const float shift = beta[lane] - rmean[lane] * scale;

    const int wave   = blockIdx.x * 4 + wid;
    const int nwaves = gridDim.x * 4;
    for (int i = wave; i < n; i += nwaves) {
        t_lds[wid][lane] = t[(size_t)i * DIM + lane];
        float y = b1v;
#pragma unroll
        for (int d4 = 0; d4 < 16; ++d4) {
            float4 t4 = *reinterpret_cast<const float4*>(&t_lds[wid][4 * d4]);
            y += t4.x * w1v[d4].x + t4.y * w1v[d4].y + t4.z * w1v[d4].z + t4.w * w1v[d4].w;
        }
        float u = fmaxf(y * scale + shift, 0.0f);  // BN(eval) + ReLU
        t_lds[wid][lane] = u;
        float y2 = b2v;
#pragma unroll
        for (int d4 = 0; d4 < 16; ++d4) {
            float4 u4 = *reinterpret_cast<const float4*>(&t_lds[wid][4 * d4]);
            y2 += u4.x * w2v[d4].x + u4.y * w2v[d4].y + u4.z * w2v[d4].z + u4.w * w2v[d4].w;
        }
        h_out[(size_t)i * DIM + lane] = fmaxf(y2, 0.0f);
    }
}

// ---------------- global_add_pool (batch sorted -> run-length + atomics) --------

__global__ void pool_kernel(const float* __restrict__ h, const int* __restrict__ batch,
                            float* __restrict__ pooled, int n) {
    const int lane = threadIdx.x & 63;
    const int wid  = threadIdx.x >> 6;
    const int wave = blockIdx.x * 4 + wid;
    const int nwaves = gridDim.x * 4;
    const int per = (n + nwaves - 1) / nwaves;
    const int a = wave * per;
    const int b = min(a + per, n);
    if (a >= b) return;
    int cur = batch[a];
    float sum = 0.0f;
    for (int i = a; i < b; ++i) {
        int g = batch[i];
        if (g != cur) {
            atomicAdd(&pooled[cur * DIM + lane], sum);
            sum = 0.0f;
            cur = g;
        }
        sum += h[(size_t)i * DIM + lane];
    }
    atomicAdd(&pooled[cur * DIM + lane], sum);
}

// ---------------- head: relu(pooled@lin1+b1) @ lin2 + b2 ----------------

__global__ void head_kernel(const float* __restrict__ pooled,
                            const float* __restrict__ w1, const float* __restrict__ b1,
                            const float* __restrict__ w2, const float* __restrict__ b2,
                            float* __restrict__ out) {
    const int g = blockIdx.x;
    const int lane = threadIdx.x;  // 64 threads = 1 wave
    __shared__ float pl[DIM];
    __shared__ float y1l[DIM];
    pl[lane] = pooled[g * DIM + lane];
    __syncthreads();
    float y = b1[lane];
#pragma unroll
    for (int d = 0; d < DIM; ++d) y += pl[d] * w1[d * DIM + lane];
    y1l[lane] = fmaxf(y, 0.0f);
    __syncthreads();
    if (lane < OUT_DIM) {
        float y2 = b2[lane];
#pragma unroll
        for (int d = 0; d < DIM; ++d) y2 += y1l[d] * w2[d * OUT_DIM + lane];
        out[g * OUT_DIM + lane] = y2;
    }
}

// ---------------- launch ----------------

extern "C" void kernel_launch(void* const* d_in, const int* in_sizes, int n_in,
                              void* d_out, int out_size, void* d_ws, size_t ws_size,
                              hipStream_t stream) {
    const float* x     = (const float*)d_in[0];
    const int*   eidx  = (const int*)  d_in[1];   // [2, N_EDGES]: src row then dst row
    const int*   batch = (const int*)  d_in[2];
    const float* W1    = (const float*)d_in[3];
    const float* b1    = (const float*)d_in[4];
    const float* gamma = (const float*)d_in[5];
    const float* beta  = (const float*)d_in[6];
    const float* rmean = (const float*)d_in[7];
    const float* rvar  = (const float*)d_in[8];
    const float* W2    = (const float*)d_in[9];
    const float* b2    = (const float*)d_in[10];
    const float* l1w   = (const float*)d_in[11];
    const float* l1b   = (const float*)d_in[12];
    const float* l2w   = (const float*)d_in[13];
    const float* l2b   = (const float*)d_in[14];
    float* out = (float*)d_out;

    // workspace layout (padded to keep 16B alignment)
    int* counts    = (int*)d_ws;              // 100000
    int* fillc     = counts    + 100352;      // 100000
    int* row_ptr   = fillc     + 100352;      // 100001
    int* blockSums = row_ptr   + 100352;      // 196
    int* blockOffs = blockSums + 256;         // 196
    int* col_idx   = blockOffs + 256;         // 1600000
    float* bufA    = (float*)(col_idx + 1600000 + 192);   // 100000*64 each
    float* bufB    = bufA + (size_t)N_NODES * DIM;
    float* bufC    = bufB + (size_t)N_NODES * DIM;
    float* pooled  = bufC + (size_t)N_NODES * DIM;

    const int* srcp = eidx;
    const int* dstp = eidx + N_EDGES;

    hipMemsetAsync(counts, 0, N_NODES * sizeof(int), stream);
    hipMemsetAsync(fillc,  0, N_NODES * sizeof(int), stream);
    hipMemsetAsync(pooled, 0, N_GRAPHS * DIM * sizeof(float), stream);

    count_kernel<<<1024, 256, 0, stream>>>(dstp, counts, N_EDGES);
    scanA_kernel<<<SCAN_NB, 256, 0, stream>>>(counts, blockSums, N_NODES);
    scanB_kernel<<<1, 256, 0, stream>>>(blockSums, blockOffs, row_ptr);
    scanC_kernel<<<SCAN_NB, 256, 0, stream>>>(counts, blockOffs, row_ptr, N_NODES);
    fill_kernel<<<1024, 256, 0, stream>>>(srcp, dstp, row_ptr, fillc, col_idx, N_EDGES);

    const int agg_blocks = (N_NODES * 64 + 255) / 256;  // one wave per node
    const int mlp_blocks = 782;                          // ~32 nodes per wave

    // buffer rotation: layer inputs/outputs never alias t
    const float* hin = x;
    float* outs[5] = {bufB, bufC, bufB, bufC, bufB};
    for (int l = 0; l < 5; ++l) {
        float* tbuf = bufA;
        float* hout = outs[l];
        agg_kernel<<<agg_blocks, 256, 0, stream>>>(hin, tbuf, row_ptr, col_idx, N_NODES);
        mlp_kernel<<<mlp_blocks, 256, 0, stream>>>(
            tbuf, hout,
            W1 + (size_t)l * DIM * DIM, b1 + (size_t)l * DIM,
            gamma + (size_t)l * DIM, beta + (size_t)l * DIM,
            rmean + (size_t)l * DIM, rvar + (size_t)l * DIM,
            W2 + (size_t)l * DIM * DIM, b2 + (size_t)l * DIM, N_NODES);
        hin = hout;
    }
    pool_kernel<<<2048, 256, 0, stream>>>(outs[4], batch, pooled, N_NODES);
    head_kernel<<<N_GRAPHS, 64, 0, stream>>>(pooled, l1w, l1b, l2w, l2b, out);
}

// Round 5
// 934.129 us; speedup vs baseline: 1.9483x; 1.0422x over previous
//
#include <hip/hip_runtime.h>

#define N_NODES  100000
#define N_EDGES  1600000
#define DIM      64
#define N_GRAPHS 128
#define OUT_DIM  10
#define SCAN_NB    196
#define SCAN_CHUNK 512   // 196*512 = 100352 >= N_NODES; 2 elems/thread @256 threads

typedef unsigned int uint;
typedef unsigned short ushort;

__device__ __forceinline__ uint f2bf(float x) {   // fp32 -> bf16 bits (RNE)
    uint b = __float_as_uint(x);
    b += 0x7fffu + ((b >> 16) & 1u);
    return b >> 16;
}

// ---------------- CSR build (bucket edges by dst) ----------------

__global__ void count_kernel(const int* __restrict__ dst, int* __restrict__ counts, int n) {
    int i = blockIdx.x * blockDim.x + threadIdx.x;
    int stride = gridDim.x * blockDim.x;
    for (; i < n; i += stride) atomicAdd(&counts[dst[i]], 1);
}

__global__ void scanA_kernel(const int* __restrict__ counts, int* __restrict__ blockSums, int n) {
    __shared__ int red[256];
    const int b = blockIdx.x, t = threadIdx.x;
    const int base = b * SCAN_CHUNK + t * 2;
    int s = 0;
    if (base < n)     s += counts[base];
    if (base + 1 < n) s += counts[base + 1];
    red[t] = s;
    __syncthreads();
    for (int off = 128; off > 0; off >>= 1) {
        if (t < off) red[t] += red[t + off];
        __syncthreads();
    }
    if (t == 0) blockSums[b] = red[0];
}

__global__ void scanB_kernel(const int* __restrict__ blockSums, int* __restrict__ blockOffs,
                             int* __restrict__ row_ptr) {
    __shared__ int sc[256];
    const int t = threadIdx.x;
    const int v = (t < SCAN_NB) ? blockSums[t] : 0;
    sc[t] = v;
    __syncthreads();
    for (int off = 1; off < 256; off <<= 1) {
        int u = (t >= off) ? sc[t - off] : 0;
        __syncthreads();
        sc[t] += u;
        __syncthreads();
    }
    if (t < SCAN_NB) blockOffs[t] = sc[t] - v;   // exclusive block offset
    if (t == 255) row_ptr[N_NODES] = sc[255];    // total == N_EDGES
}

// also initializes fillc = row_ptr so fill_kernel needs only ONE random access
__global__ void scanC_kernel(const int* __restrict__ counts, const int* __restrict__ blockOffs,
                             int* __restrict__ row_ptr, int* __restrict__ fillc, int n) {
    __shared__ int sc[256];
    const int b = blockIdx.x, t = threadIdx.x;
    const int base = b * SCAN_CHUNK + t * 2;
    const int c0 = (base < n) ? counts[base] : 0;
    const int c1 = (base + 1 < n) ? counts[base + 1] : 0;
    const int s = c0 + c1;
    sc[t] = s;
    __syncthreads();
    for (int off = 1; off < 256; off <<= 1) {
        int u = (t >= off) ? sc[t - off] : 0;
        __syncthreads();
        sc[t] += u;
        __syncthreads();
    }
    const int pre = blockOffs[b] + sc[t] - s;    // exclusive prefix for base
    if (base < n)     { row_ptr[base]     = pre;      fillc[base]     = pre; }
    if (base + 1 < n) { row_ptr[base + 1] = pre + c0; fillc[base + 1] = pre + c0; }
}

__global__ void fill_kernel(const int* __restrict__ src, const int* __restrict__ dst,
                            int* __restrict__ fillc, int* __restrict__ col_idx, int n) {
    int i = blockIdx.x * blockDim.x + threadIdx.x;
    int stride = gridDim.x * blockDim.x;
    for (; i < n; i += stride) {
        int pos = atomicAdd(&fillc[dst[i]], 1);
        col_idx[pos] = src[i];
    }
}

// ---------------- x (fp32) -> bf16 rows ----------------

__global__ void cvt_kernel(const float* __restrict__ x, ushort* __restrict__ xb, int n4) {
    int idx = blockIdx.x * blockDim.x + threadIdx.x;
    if (idx >= n4) return;
    float4 v = ((const float4*)x)[idx];
    uint2 o;
    o.x = f2bf(v.x) | (f2bf(v.y) << 16);
    o.y = f2bf(v.z) | (f2bf(v.w) << 16);
    ((uint2*)xb)[idx] = o;
}

// ---------------- Aggregation: t[i] = hb[i] + sum_{j in N(i)} hb[j]  (bf16 rows) ----
// One wave per node. Row = 64 bf16 = 128B = one cache line = 8 x 16B chunks.
// Lane = (r,q): r = row-slot (8 rows per dwordx4 instruction), q = 16B chunk.
// fp32 accumulate; shfl_xor reduce across r. SELF TERM ADDED ONCE, AFTER
// THE REDUCTION (adding it in init counts it 8x — the R4 bug).

__device__ __forceinline__ void add_unpack(float acc[8], uint4 v) {
    acc[0] += __uint_as_float(v.x << 16);
    acc[1] += __uint_as_float(v.x & 0xffff0000u);
    acc[2] += __uint_as_float(v.y << 16);
    acc[3] += __uint_as_float(v.y & 0xffff0000u);
    acc[4] += __uint_as_float(v.z << 16);
    acc[5] += __uint_as_float(v.z & 0xffff0000u);
    acc[6] += __uint_as_float(v.w << 16);
    acc[7] += __uint_as_float(v.w & 0xffff0000u);
}

__global__ __launch_bounds__(256) void agg_kernel(
    const ushort* __restrict__ hb, float* __restrict__ t,
    const int* __restrict__ row_ptr, const int* __restrict__ col_idx, int n)
{
    const uint4* __restrict__ hb4 = (const uint4*)hb;   // row = 8 uint4
    const int lane = threadIdx.x & 63;
    const int r = lane >> 3;     // row slot 0..7
    const int q = lane & 7;      // 16B chunk 0..7
    const int i = (blockIdx.x * blockDim.x + threadIdx.x) >> 6;
    if (i >= n) return;
    const int start = row_ptr[i];
    const int end   = row_ptr[i + 1];

    float acc[8] = {0.f, 0.f, 0.f, 0.f, 0.f, 0.f, 0.f, 0.f};

    for (int e0 = start; e0 < end; e0 += 64) {
        const int navail = end - e0;
        const int cnt = min(64, navail);
        int myidx = (lane < navail) ? col_idx[e0 + lane] : 0;
        int g = 0;
        for (; g + 16 <= cnt; g += 16) {   // 16 rows, 2 dwordx4 gathers in flight
            int sa = __shfl(myidx, g + r);
            int sb = __shfl(myidx, g + 8 + r);
            uint4 va = hb4[(size_t)sa * 8 + q];
            uint4 vb = hb4[(size_t)sb * 8 + q];
            add_unpack(acc, va);
            add_unpack(acc, vb);
        }
        if (g < cnt) {   // masked tail (up to 15 rows), no serial remainder
            {
                int row = g + r;
                bool valid = row < cnt;
                int sk = __shfl(myidx, valid ? row : 0);
                uint4 v = hb4[(size_t)sk * 8 + q];
                if (valid) add_unpack(acc, v);
            }
            {
                int row = g + 8 + r;
                bool valid = row < cnt;
                int sk = __shfl(myidx, valid ? row : 0);
                uint4 v = hb4[(size_t)sk * 8 + q];
                if (valid) add_unpack(acc, v);
            }
        }
    }
    // reduce across the 8 r-slots (lane bits 3,4,5)
#pragma unroll
    for (int k = 0; k < 8; ++k) {
        acc[k] += __shfl_xor(acc[k], 8);
        acc[k] += __shfl_xor(acc[k], 16);
        acc[k] += __shfl_xor(acc[k], 32);
    }
    if (lane < 8) {   // lane holds fp32 columns lane*8..lane*8+7
        uint4 self = hb4[(size_t)i * 8 + lane];   // self term (eps = 0), ONCE
        add_unpack(acc, self);
        float4* t4 = (float4*)t;
        t4[(size_t)i * 16 + 2 * lane]     = make_float4(acc[0], acc[1], acc[2], acc[3]);
        t4[(size_t)i * 16 + 2 * lane + 1] = make_float4(acc[4], acc[5], acc[6], acc[7]);
    }
}

// ---------------- MLP: hb_out = bf16( relu( relu(BN(t@W1+b1)) @ W2 + b2 ) ) --------
// fp32 compute throughout; only the inter-layer storage is bf16.

__global__ __launch_bounds__(256) void mlp_kernel(
    const float* __restrict__ t, ushort* __restrict__ hb_out,
    const float* __restrict__ W1, const float* __restrict__ b1,
    const float* __restrict__ gamma, const float* __restrict__ beta,
    const float* __restrict__ rmean, const float* __restrict__ rvar,
    const float* __restrict__ W2, const float* __restrict__ b2, int n)
{
    __shared__ __align__(16) float t_lds[4][DIM];
    const int lane = threadIdx.x & 63;
    const int wid  = threadIdx.x >> 6;

    float4 w1v[16], w2v[16];
#pragma unroll
    for (int d4 = 0; d4 < 16; ++d4) {
        w1v[d4] = make_float4(W1[(4 * d4 + 0) * DIM + lane], W1[(4 * d4 + 1) * DIM + lane],
                              W1[(4 * d4 + 2) * DIM + lane], W1[(4 * d4 + 3) * DIM + lane]);
        w2v[d4] = make_float4(W2[(4 * d4 + 0) * DIM + lane], W2[(4 * d4 + 1) * DIM + lane],
                              W2[(4 * d4 + 2) * DIM + lane], W2[(4 * d4 + 3) * DIM + lane]);
    }
    const float b1v = b1[lane], b2v = b2[lane];
    const float scale = gamma[lane] * rsqrtf(rvar[lane] + 1e-5f);
    const float shift = beta[lane] - rmean[lane] * scale;

    const int wave   = blockIdx.x * 4 + wid;
    const int nwaves = gridDim.x * 4;
    for (int i = wave; i < n; i += nwaves) {
        t_lds[wid][lane] = t[(size_t)i * DIM + lane];
        float y = b1v;
#pragma unroll
        for (int d4 = 0; d4 < 16; ++d4) {
            float4 t4 = *reinterpret_cast<const float4*>(&t_lds[wid][4 * d4]);
            y += t4.x * w1v[d4].x + t4.y * w1v[d4].y + t4.z * w1v[d4].z + t4.w * w1v[d4].w;
        }
        float u = fmaxf(y * scale + shift, 0.0f);  // BN(eval) + ReLU
        t_lds[wid][lane] = u;
        float y2 = b2v;
#pragma unroll
        for (int d4 = 0; d4 < 16; ++d4) {
            float4 u4 = *reinterpret_cast<const float4*>(&t_lds[wid][4 * d4]);
            y2 += u4.x * w2v[d4].x + u4.y * w2v[d4].y + u4.z * w2v[d4].z + u4.w * w2v[d4].w;
        }
        hb_out[(size_t)i * DIM + lane] = (ushort)f2bf(fmaxf(y2, 0.0f));
    }
}

// ---------------- global_add_pool (batch sorted -> run-length + atomics) --------

__global__ void pool_kernel(const ushort* __restrict__ hb, const int* __restrict__ batch,
                            float* __restrict__ pooled, int n) {
    const int lane = threadIdx.x & 63;
    const int wid  = threadIdx.x >> 6;
    const int wave = blockIdx.x * 4 + wid;
    const int nwaves = gridDim.x * 4;
    const int per = (n + nwaves - 1) / nwaves;
    const int a = wave * per;
    const int b = min(a + per, n);
    if (a >= b) return;
    int cur = batch[a];
    float sum = 0.0f;
    for (int i = a; i < b; ++i) {
        int g = batch[i];
        if (g != cur) {
            atomicAdd(&pooled[cur * DIM + lane], sum);
            sum = 0.0f;
            cur = g;
        }
        sum += __uint_as_float(((uint)hb[(size_t)i * DIM + lane]) << 16);
    }
    atomicAdd(&pooled[cur * DIM + lane], sum);
}

// ---------------- head: relu(pooled@lin1+b1) @ lin2 + b2 ----------------

__global__ void head_kernel(const float* __restrict__ pooled,
                            const float* __restrict__ w1, const float* __restrict__ b1,
                            const float* __restrict__ w2, const float* __restrict__ b2,
                            float* __restrict__ out) {
    const int g = blockIdx.x;
    const int lane = threadIdx.x;  // 64 threads = 1 wave
    __shared__ float pl[DIM];
    __shared__ float y1l[DIM];
    pl[lane] = pooled[g * DIM + lane];
    __syncthreads();
    float y = b1[lane];
#pragma unroll
    for (int d = 0; d < DIM; ++d) y += pl[d] * w1[d * DIM + lane];
    y1l[lane] = fmaxf(y, 0.0f);
    __syncthreads();
    if (lane < OUT_DIM) {
        float y2 = b2[lane];
#pragma unroll
        for (int d = 0; d < DIM; ++d) y2 += y1l[d] * w2[d * OUT_DIM + lane];
        out[g * OUT_DIM + lane] = y2;
    }
}

// ---------------- launch ----------------

extern "C" void kernel_launch(void* const* d_in, const int* in_sizes, int n_in,
                              void* d_out, int out_size, void* d_ws, size_t ws_size,
                              hipStream_t stream) {
    const float* x     = (const float*)d_in[0];
    const int*   eidx  = (const int*)  d_in[1];   // [2, N_EDGES]: src row then dst row
    const int*   batch = (const int*)  d_in[2];
    const float* W1    = (const float*)d_in[3];
    const float* b1    = (const float*)d_in[4];
    const float* gamma = (const float*)d_in[5];
    const float* beta  = (const float*)d_in[6];
    const float* rmean = (const float*)d_in[7];
    const float* rvar  = (const float*)d_in[8];
    const float* W2    = (const float*)d_in[9];
    const float* b2    = (const float*)d_in[10];
    const float* l1w   = (const float*)d_in[11];
    const float* l1b   = (const float*)d_in[12];
    const float* l2w   = (const float*)d_in[13];
    const float* l2b   = (const float*)d_in[14];
    float* out = (float*)d_out;

    // workspace layout (padded, 16B-aligned pieces)
    int* counts    = (int*)d_ws;              // 100000
    int* fillc     = counts    + 100352;      // 100000
    int* row_ptr   = fillc     + 100352;      // 100001
    int* blockSums = row_ptr   + 100352;      // 196
    int* blockOffs = blockSums + 256;         // 196
    int* col_idx   = blockOffs + 256;         // 1600000
    float*  tbuf   = (float*)(col_idx + 1600000 + 192);   // 100000*64 fp32 (25.6MB)
    ushort* hbuf   = (ushort*)(tbuf + (size_t)N_NODES * DIM);  // 100000*64 bf16 (12.8MB)
    float* pooled  = (float*)(hbuf + (size_t)N_NODES * DIM);

    const int* srcp = eidx;
    const int* dstp = eidx + N_EDGES;

    hipMemsetAsync(counts, 0, N_NODES * sizeof(int), stream);
    hipMemsetAsync(pooled, 0, N_GRAPHS * DIM * sizeof(float), stream);

    cvt_kernel<<<(N_NODES * DIM / 4 + 255) / 256, 256, 0, stream>>>(x, hbuf, N_NODES * DIM / 4);
    count_kernel<<<1024, 256, 0, stream>>>(dstp, counts, N_EDGES);
    scanA_kernel<<<SCAN_NB, 256, 0, stream>>>(counts, blockSums, N_NODES);
    scanB_kernel<<<1, 256, 0, stream>>>(blockSums, blockOffs, row_ptr);
    scanC_kernel<<<SCAN_NB, 256, 0, stream>>>(counts, blockOffs, row_ptr, fillc, N_NODES);
    fill_kernel<<<1024, 256, 0, stream>>>(srcp, dstp, fillc, col_idx, N_EDGES);

    const int agg_blocks = (N_NODES * 64 + 255) / 256;  // one wave per node
    const int mlp_blocks = 782;                          // ~32 nodes per wave

    for (int l = 0; l < 5; ++l) {
        agg_kernel<<<agg_blocks, 256, 0, stream>>>(hbuf, tbuf, row_ptr, col_idx, N_NODES);
        mlp_kernel<<<mlp_blocks, 256, 0, stream>>>(
            tbuf, hbuf,
            W1 + (size_t)l * DIM * DIM, b1 + (size_t)l * DIM,
            gamma + (size_t)l * DIM, beta + (size_t)l * DIM,
            rmean + (size_t)l * DIM, rvar + (size_t)l * DIM,
            W2 + (size_t)l * DIM * DIM, b2 + (size_t)l * DIM, N_NODES);
    }
    pool_kernel<<<2048, 256, 0, stream>>>(hbuf, batch, pooled, N_NODES);
    head_kernel<<<N_GRAPHS, 64, 0, stream>>>(pooled, l1w, l1b, l2w, l2b, out);
}

// Round 6
// 854.703 us; speedup vs baseline: 2.1294x; 1.0929x over previous
//
#include <hip/hip_runtime.h>

#define N_NODES  100000
#define N_EDGES  1600000
#define DIM      64
#define N_GRAPHS 128
#define OUT_DIM  10
#define SCAN_NB    196
#define SCAN_CHUNK 512   // 196*512 = 100352 >= N_NODES; 2 elems/thread @256 threads

typedef unsigned int uint;
typedef unsigned short ushort;

__device__ __forceinline__ uint f2bf(float x) {   // fp32 -> bf16 bits (RNE)
    uint b = __float_as_uint(x);
    b += 0x7fffu + ((b >> 16) & 1u);
    return b >> 16;
}

// ---------------- CSR build (bucket edges by dst) ----------------

__global__ void count_kernel(const int* __restrict__ dst, int* __restrict__ counts, int n) {
    int i = blockIdx.x * blockDim.x + threadIdx.x;
    int stride = gridDim.x * blockDim.x;
    for (; i < n; i += stride) atomicAdd(&counts[dst[i]], 1);
}

__global__ void scanA_kernel(const int* __restrict__ counts, int* __restrict__ blockSums, int n) {
    __shared__ int red[256];
    const int b = blockIdx.x, t = threadIdx.x;
    const int base = b * SCAN_CHUNK + t * 2;
    int s = 0;
    if (base < n)     s += counts[base];
    if (base + 1 < n) s += counts[base + 1];
    red[t] = s;
    __syncthreads();
    for (int off = 128; off > 0; off >>= 1) {
        if (t < off) red[t] += red[t + off];
        __syncthreads();
    }
    if (t == 0) blockSums[b] = red[0];
}

__global__ void scanB_kernel(const int* __restrict__ blockSums, int* __restrict__ blockOffs,
                             int* __restrict__ row_ptr) {
    __shared__ int sc[256];
    const int t = threadIdx.x;
    const int v = (t < SCAN_NB) ? blockSums[t] : 0;
    sc[t] = v;
    __syncthreads();
    for (int off = 1; off < 256; off <<= 1) {
        int u = (t >= off) ? sc[t - off] : 0;
        __syncthreads();
        sc[t] += u;
        __syncthreads();
    }
    if (t < SCAN_NB) blockOffs[t] = sc[t] - v;   // exclusive block offset
    if (t == 255) row_ptr[N_NODES] = sc[255];    // total == N_EDGES
}

// also initializes fillc = row_ptr so fill_kernel needs only ONE random access
__global__ void scanC_kernel(const int* __restrict__ counts, const int* __restrict__ blockOffs,
                             int* __restrict__ row_ptr, int* __restrict__ fillc, int n) {
    __shared__ int sc[256];
    const int b = blockIdx.x, t = threadIdx.x;
    const int base = b * SCAN_CHUNK + t * 2;
    const int c0 = (base < n) ? counts[base] : 0;
    const int c1 = (base + 1 < n) ? counts[base + 1] : 0;
    const int s = c0 + c1;
    sc[t] = s;
    __syncthreads();
    for (int off = 1; off < 256; off <<= 1) {
        int u = (t >= off) ? sc[t - off] : 0;
        __syncthreads();
        sc[t] += u;
        __syncthreads();
    }
    const int pre = blockOffs[b] + sc[t] - s;    // exclusive prefix for base
    if (base < n)     { row_ptr[base]     = pre;      fillc[base]     = pre; }
    if (base + 1 < n) { row_ptr[base + 1] = pre + c0; fillc[base + 1] = pre + c0; }
}

// 7-pass segment-filtered scatter: pass p touches only col_idx slots for
// dst in [p*16384, (p+1)*16384) -> ~1MB window stays L2-resident, write
// lines get fully merged before eviction (kills the 16x write amplification).
__global__ void fill_kernel(const int* __restrict__ src, const int* __restrict__ dst,
                            int* __restrict__ fillc, int* __restrict__ col_idx, int n) {
    const int tid0 = blockIdx.x * blockDim.x + threadIdx.x;
    const int stride = gridDim.x * blockDim.x;
    for (int pass = 0; pass < 7; ++pass) {
        for (int i = tid0; i < n; i += stride) {
            int d = dst[i];
            if ((d >> 14) == pass) {
                int pos = atomicAdd(&fillc[d], 1);
                col_idx[pos] = src[i];
            }
        }
    }
}

// ---------------- x (fp32) -> bf16 rows ----------------

__global__ void cvt_kernel(const float* __restrict__ x, ushort* __restrict__ xb, int n4) {
    int idx = blockIdx.x * blockDim.x + threadIdx.x;
    if (idx >= n4) return;
    float4 v = ((const float4*)x)[idx];
    uint2 o;
    o.x = f2bf(v.x) | (f2bf(v.y) << 16);
    o.y = f2bf(v.z) | (f2bf(v.w) << 16);
    ((uint2*)xb)[idx] = o;
}

// ---------------- Aggregation: t[i] = hb[i] + sum_{j in N(i)} hb[j]  (bf16 rows) ----
// GROUP-PER-NODE: 8 lanes own one node (8 x 16B = full 128B bf16 row); one wave
// handles 8 nodes. No shfl/bpermute, no cross-lane reduction (each lane owns
// distinct output dims -> self term in init is correct here). col_idx indices
// come from direct broadcast loads (8 addrs/wave, L1-hot). 4-deep unroll ->
// 4 independent dwordx4 gathers in flight per wave.

__device__ __forceinline__ void add_unpack(float acc[8], uint4 v) {
    acc[0] += __uint_as_float(v.x << 16);
    acc[1] += __uint_as_float(v.x & 0xffff0000u);
    acc[2] += __uint_as_float(v.y << 16);
    acc[3] += __uint_as_float(v.y & 0xffff0000u);
    acc[4] += __uint_as_float(v.z << 16);
    acc[5] += __uint_as_float(v.z & 0xffff0000u);
    acc[6] += __uint_as_float(v.w << 16);
    acc[7] += __uint_as_float(v.w & 0xffff0000u);
}

__global__ __launch_bounds__(256) void agg_kernel(
    const ushort* __restrict__ hb, float* __restrict__ t,
    const int* __restrict__ row_ptr, const int* __restrict__ col_idx, int n)
{
    const uint4* __restrict__ hb4 = (const uint4*)hb;   // row = 8 uint4
    const int lane = threadIdx.x & 63;
    const int g = lane >> 3;     // node slot 0..7 within wave
    const int q = lane & 7;      // 16B chunk 0..7 within row
    const int wave = (blockIdx.x * blockDim.x + threadIdx.x) >> 6;
    const int i = wave * 8 + g;
    if (i >= n) return;
    const int rp0 = row_ptr[i];
    const int deg = row_ptr[i + 1] - rp0;

    float acc[8];
    {   // self term (eps = 0) — safe in init: no cross-lane reduction follows
        uint4 v = hb4[(size_t)i * 8 + q];
        acc[0] = __uint_as_float(v.x << 16);
        acc[1] = __uint_as_float(v.x & 0xffff0000u);
        acc[2] = __uint_as_float(v.y << 16);
        acc[3] = __uint_as_float(v.y & 0xffff0000u);
        acc[4] = __uint_as_float(v.z << 16);
        acc[5] = __uint_as_float(v.z & 0xffff0000u);
        acc[6] = __uint_as_float(v.w << 16);
        acc[7] = __uint_as_float(v.w & 0xffff0000u);
    }

    int e = 0;
    for (; e + 4 <= deg; e += 4) {   // 4 gathers in flight per group
        int i0 = col_idx[rp0 + e];
        int i1 = col_idx[rp0 + e + 1];
        int i2 = col_idx[rp0 + e + 2];
        int i3 = col_idx[rp0 + e + 3];
        uint4 v0 = hb4[(size_t)i0 * 8 + q];
        uint4 v1 = hb4[(size_t)i1 * 8 + q];
        uint4 v2 = hb4[(size_t)i2 * 8 + q];
        uint4 v3 = hb4[(size_t)i3 * 8 + q];
        add_unpack(acc, v0);
        add_unpack(acc, v1);
        add_unpack(acc, v2);
        add_unpack(acc, v3);
    }
    for (; e < deg; ++e) {           // remainder <= 3
        int ix = col_idx[rp0 + e];
        uint4 v = hb4[(size_t)ix * 8 + q];
        add_unpack(acc, v);
    }

    float4* t4 = (float4*)t;   // lane (g,q) owns fp32 dims q*8 .. q*8+7 of node i
    t4[(size_t)i * 16 + 2 * q]     = make_float4(acc[0], acc[1], acc[2], acc[3]);
    t4[(size_t)i * 16 + 2 * q + 1] = make_float4(acc[4], acc[5], acc[6], acc[7]);
}

// ---------------- MLP: hb_out = bf16( relu( relu(BN(t@W1+b1)) @ W2 + b2 ) ) --------
// fp32 compute throughout; only the inter-layer storage is bf16.

__global__ __launch_bounds__(256) void mlp_kernel(
    const float* __restrict__ t, ushort* __restrict__ hb_out,
    const float* __restrict__ W1, const float* __restrict__ b1,
    const float* __restrict__ gamma, const float* __restrict__ beta,
    const float* __restrict__ rmean, const float* __restrict__ rvar,
    const float* __restrict__ W2, const float* __restrict__ b2, int n)
{
    __shared__ __align__(16) float t_lds[4][DIM];
    const int lane = threadIdx.x & 63;
    const int wid  = threadIdx.x >> 6;

    float4 w1v[16], w2v[16];
#pragma unroll
    for (int d4 = 0; d4 < 16; ++d4) {
        w1v[d4] = make_float4(W1[(4 * d4 + 0) * DIM + lane], W1[(4 * d4 + 1) * DIM + lane],
                              W1[(4 * d4 + 2) * DIM + lane], W1[(4 * d4 + 3) * DIM + lane]);
        w2v[d4] = make_float4(W2[(4 * d4 + 0) * DIM + lane], W2[(4 * d4 + 1) * DIM + lane],
                              W2[(4 * d4 + 2) * DIM + lane], W2[(4 * d4 + 3) * DIM + lane]);
    }
    const float b1v = b1[lane], b2v = b2[lane];
    const float scale = gamma[lane] * rsqrtf(rvar[lane] + 1e-5f);
    const float shift = beta[lane] - rmean[lane] * scale;

    const int wave   = blockIdx.x * 4 + wid;
    const int nwaves = gridDim.x * 4;
    for (int i = wave; i < n; i += nwaves) {
        t_lds[wid][lane] = t[(size_t)i * DIM + lane];
        float y = b1v;
#pragma unroll
        for (int d4 = 0; d4 < 16; ++d4) {
            float4 t4 = *reinterpret_cast<const float4*>(&t_lds[wid][4 * d4]);
            y += t4.x * w1v[d4].x + t4.y * w1v[d4].y + t4.z * w1v[d4].z + t4.w * w1v[d4].w;
        }
        float u = fmaxf(y * scale + shift, 0.0f);  // BN(eval) + ReLU
        t_lds[wid][lane] = u;
        float y2 = b2v;
#pragma unroll
        for (int d4 = 0; d4 < 16; ++d4) {
            float4 u4 = *reinterpret_cast<const float4*>(&t_lds[wid][4 * d4]);
            y2 += u4.x * w2v[d4].x + u4.y * w2v[d4].y + u4.z * w2v[d4].z + u4.w * w2v[d4].w;
        }
        hb_out[(size_t)i * DIM + lane] = (ushort)f2bf(fmaxf(y2, 0.0f));
    }
}

// ---------------- global_add_pool (batch sorted -> run-length + atomics) --------

__global__ void pool_kernel(const ushort* __restrict__ hb, const int* __restrict__ batch,
                            float* __restrict__ pooled, int n) {
    const int lane = threadIdx.x & 63;
    const int wid  = threadIdx.x >> 6;
    const int wave = blockIdx.x * 4 + wid;
    const int nwaves = gridDim.x * 4;
    const int per = (n + nwaves - 1) / nwaves;
    const int a = wave * per;
    const int b = min(a + per, n);
    if (a >= b) return;
    int cur = batch[a];
    float sum = 0.0f;
    for (int i = a; i < b; ++i) {
        int g = batch[i];
        if (g != cur) {
            atomicAdd(&pooled[cur * DIM + lane], sum);
            sum = 0.0f;
            cur = g;
        }
        sum += __uint_as_float(((uint)hb[(size_t)i * DIM + lane]) << 16);
    }
    atomicAdd(&pooled[cur * DIM + lane], sum);
}

// ---------------- head: relu(pooled@lin1+b1) @ lin2 + b2 ----------------

__global__ void head_kernel(const float* __restrict__ pooled,
                            const float* __restrict__ w1, const float* __restrict__ b1,
                            const float* __restrict__ w2, const float* __restrict__ b2,
                            float* __restrict__ out) {
    const int g = blockIdx.x;
    const int lane = threadIdx.x;  // 64 threads = 1 wave
    __shared__ float pl[DIM];
    __shared__ float y1l[DIM];
    pl[lane] = pooled[g * DIM + lane];
    __syncthreads();
    float y = b1[lane];
#pragma unroll
    for (int d = 0; d < DIM; ++d) y += pl[d] * w1[d * DIM + lane];
    y1l[lane] = fmaxf(y, 0.0f);
    __syncthreads();
    if (lane < OUT_DIM) {
        float y2 = b2[lane];
#pragma unroll
        for (int d = 0; d < DIM; ++d) y2 += y1l[d] * w2[d * OUT_DIM + lane];
        out[g * OUT_DIM + lane] = y2;
    }
}

// ---------------- launch ----------------

extern "C" void kernel_launch(void* const* d_in, const int* in_sizes, int n_in,
                              void* d_out, int out_size, void* d_ws, size_t ws_size,
                              hipStream_t stream) {
    const float* x     = (const float*)d_in[0];
    const int*   eidx  = (const int*)  d_in[1];   // [2, N_EDGES]: src row then dst row
    const int*   batch = (const int*)  d_in[2];
    const float* W1    = (const float*)d_in[3];
    const float* b1    = (const float*)d_in[4];
    const float* gamma = (const float*)d_in[5];
    const float* beta  = (const float*)d_in[6];
    const float* rmean = (const float*)d_in[7];
    const float* rvar  = (const float*)d_in[8];
    const float* W2    = (const float*)d_in[9];
    const float* b2    = (const float*)d_in[10];
    const float* l1w   = (const float*)d_in[11];
    const float* l1b   = (const float*)d_in[12];
    const float* l2w   = (const float*)d_in[13];
    const float* l2b   = (const float*)d_in[14];
    float* out = (float*)d_out;

    // workspace layout (padded, 16B-aligned pieces)
    int* counts    = (int*)d_ws;              // 100000
    int* fillc     = counts    + 100352;      // 100000
    int* row_ptr   = fillc     + 100352;      // 100001
    int* blockSums = row_ptr   + 100352;      // 196
    int* blockOffs = blockSums + 256;         // 196
    int* col_idx   = blockOffs + 256;         // 1600000
    float*  tbuf   = (float*)(col_idx + 1600000 + 192);   // 100000*64 fp32 (25.6MB)
    ushort* hbuf   = (ushort*)(tbuf + (size_t)N_NODES * DIM);  // 100000*64 bf16 (12.8MB)
    float* pooled  = (float*)(hbuf + (size_t)N_NODES * DIM);

    const int* srcp = eidx;
    const int* dstp = eidx + N_EDGES;

    hipMemsetAsync(counts, 0, N_NODES * sizeof(int), stream);
    hipMemsetAsync(pooled, 0, N_GRAPHS * DIM * sizeof(float), stream);

    cvt_kernel<<<(N_NODES * DIM / 4 + 255) / 256, 256, 0, stream>>>(x, hbuf, N_NODES * DIM / 4);
    count_kernel<<<1024, 256, 0, stream>>>(dstp, counts, N_EDGES);
    scanA_kernel<<<SCAN_NB, 256, 0, stream>>>(counts, blockSums, N_NODES);
    scanB_kernel<<<1, 256, 0, stream>>>(blockSums, blockOffs, row_ptr);
    scanC_kernel<<<SCAN_NB, 256, 0, stream>>>(counts, blockOffs, row_ptr, fillc, N_NODES);
    fill_kernel<<<1024, 256, 0, stream>>>(srcp, dstp, fillc, col_idx, N_EDGES);

    const int agg_blocks = ((N_NODES + 7) / 8 * 64 + 255) / 256;  // 8 nodes per wave
    const int mlp_blocks = 782;                                    // ~32 nodes per wave

    for (int l = 0; l < 5; ++l) {
        agg_kernel<<<agg_blocks, 256, 0, stream>>>(hbuf, tbuf, row_ptr, col_idx, N_NODES);
        mlp_kernel<<<mlp_blocks, 256, 0, stream>>>(
            tbuf, hbuf,
            W1 + (size_t)l * DIM * DIM, b1 + (size_t)l * DIM,
            gamma + (size_t)l * DIM, beta + (size_t)l * DIM,
            rmean + (size_t)l * DIM, rvar + (size_t)l * DIM,
            W2 + (size_t)l * DIM * DIM, b2 + (size_t)l * DIM, N_NODES);
    }
    pool_kernel<<<2048, 256, 0, stream>>>(hbuf, batch, pooled, N_NODES);
    head_kernel<<<N_GRAPHS, 64, 0, stream>>>(pooled, l1w, l1b, l2w, l2b, out);
}

// Round 7
// 485.348 us; speedup vs baseline: 3.7498x; 1.7610x over previous
//
#include <hip/hip_runtime.h>

#define N_NODES  100000
#define N_EDGES  1600000
#define DIM      64
#define N_GRAPHS 128
#define OUT_DIM  10
#define SCAN_NB    196
#define SCAN_CHUNK 512   // 196*512 = 100352 >= N_NODES; 2 elems/thread @256 threads

typedef unsigned int uint;
typedef unsigned short ushort;
typedef __attribute__((ext_vector_type(8))) short short8;   // 8 bf16 = 4 VGPRs
typedef __attribute__((ext_vector_type(4))) float f32x4;

__device__ __forceinline__ uint f2bf(float x) {   // fp32 -> bf16 bits (RNE)
    uint b = __float_as_uint(x);
    b += 0x7fffu + ((b >> 16) & 1u);
    return b >> 16;
}

// ---------------- CSR build (bucket edges by dst) ----------------

__global__ void count_kernel(const int* __restrict__ dst, int* __restrict__ counts, int n) {
    int i = blockIdx.x * blockDim.x + threadIdx.x;
    int stride = gridDim.x * blockDim.x;
    for (; i < n; i += stride) atomicAdd(&counts[dst[i]], 1);
}

__global__ void scanA_kernel(const int* __restrict__ counts, int* __restrict__ blockSums, int n) {
    __shared__ int red[256];
    const int b = blockIdx.x, t = threadIdx.x;
    const int base = b * SCAN_CHUNK + t * 2;
    int s = 0;
    if (base < n)     s += counts[base];
    if (base + 1 < n) s += counts[base + 1];
    red[t] = s;
    __syncthreads();
    for (int off = 128; off > 0; off >>= 1) {
        if (t < off) red[t] += red[t + off];
        __syncthreads();
    }
    if (t == 0) blockSums[b] = red[0];
}

__global__ void scanB_kernel(const int* __restrict__ blockSums, int* __restrict__ blockOffs,
                             int* __restrict__ row_ptr) {
    __shared__ int sc[256];
    const int t = threadIdx.x;
    const int v = (t < SCAN_NB) ? blockSums[t] : 0;
    sc[t] = v;
    __syncthreads();
    for (int off = 1; off < 256; off <<= 1) {
        int u = (t >= off) ? sc[t - off] : 0;
        __syncthreads();
        sc[t] += u;
        __syncthreads();
    }
    if (t < SCAN_NB) blockOffs[t] = sc[t] - v;   // exclusive block offset
    if (t == 255) row_ptr[N_NODES] = sc[255];    // total == N_EDGES
}

// also initializes fillc = row_ptr so fill_kernel needs only ONE random access
__global__ void scanC_kernel(const int* __restrict__ counts, const int* __restrict__ blockOffs,
                             int* __restrict__ row_ptr, int* __restrict__ fillc, int n) {
    __shared__ int sc[256];
    const int b = blockIdx.x, t = threadIdx.x;
    const int base = b * SCAN_CHUNK + t * 2;
    const int c0 = (base < n) ? counts[base] : 0;
    const int c1 = (base + 1 < n) ? counts[base + 1] : 0;
    const int s = c0 + c1;
    sc[t] = s;
    __syncthreads();
    for (int off = 1; off < 256; off <<= 1) {
        int u = (t >= off) ? sc[t - off] : 0;
        __syncthreads();
        sc[t] += u;
        __syncthreads();
    }
    const int pre = blockOffs[b] + sc[t] - s;    // exclusive prefix for base
    if (base < n)     { row_ptr[base]     = pre;      fillc[base]     = pre; }
    if (base + 1 < n) { row_ptr[base + 1] = pre + c0; fillc[base + 1] = pre + c0; }
}

// 7-pass segment-filtered scatter (keeps col_idx write window L2-resident)
__global__ void fill_kernel(const int* __restrict__ src, const int* __restrict__ dst,
                            int* __restrict__ fillc, int* __restrict__ col_idx, int n) {
    const int tid0 = blockIdx.x * blockDim.x + threadIdx.x;
    const int stride = gridDim.x * blockDim.x;
    for (int pass = 0; pass < 7; ++pass) {
        for (int i = tid0; i < n; i += stride) {
            int d = dst[i];
            if ((d >> 14) == pass) {
                int pos = atomicAdd(&fillc[d], 1);
                col_idx[pos] = src[i];
            }
        }
    }
}

// ---------------- x (fp32) -> bf16 rows ----------------

__global__ void cvt_kernel(const float* __restrict__ x, ushort* __restrict__ xb, int n4) {
    int idx = blockIdx.x * blockDim.x + threadIdx.x;
    if (idx >= n4) return;
    float4 v = ((const float4*)x)[idx];
    uint2 o;
    o.x = f2bf(v.x) | (f2bf(v.y) << 16);
    o.y = f2bf(v.z) | (f2bf(v.w) << 16);
    ((uint2*)xb)[idx] = o;
}

// ---------------- Weight repack: MFMA fragment layouts, once per launch ----------
// mat 2l   = W1^T A-frags  (elem = W[k][outer*16+n15], used as A of W1^T·t^T)
// mat 2l+1 = W2   B-frags  (same index formula)
// frag f = outer*2 + h; lane (n15, quad) holds 8 bf16: W[h*32+quad*8+j][outer*16+n15]

__global__ void repack_kernel(const float* __restrict__ W1, const float* __restrict__ W2,
                              uint4* __restrict__ Wp) {
    const int wave = (blockIdx.x * blockDim.x + threadIdx.x) >> 6;
    if (wave >= 10) return;
    const int layer = wave >> 1;
    const float* W = (wave & 1) ? (W2 + layer * 4096) : (W1 + layer * 4096);
    const int lane = threadIdx.x & 63;
    const int n15 = lane & 15, quad = lane >> 4;
#pragma unroll
    for (int f = 0; f < 8; ++f) {
        const int outer = f >> 1, h = f & 1;
        uint p[4];
#pragma unroll
        for (int pj = 0; pj < 4; ++pj) {
            const int k0 = h * 32 + quad * 8 + 2 * pj;
            uint lo = f2bf(W[k0 * 64 + outer * 16 + n15]);
            uint hi = f2bf(W[(k0 + 1) * 64 + outer * 16 + n15]);
            p[pj] = lo | (hi << 16);
        }
        Wp[(wave * 8 + f) * 64 + lane] = make_uint4(p[0], p[1], p[2], p[3]);
    }
}

// ---------------- Aggregation: tb[i] = hb[i] + sum_{j in N(i)} hb[j] -> bf16 ------
// GROUP-PER-NODE (R6 structure); output now bf16 (t feeds MFMA GEMM1).

__device__ __forceinline__ void add_unpack(float acc[8], uint4 v) {
    acc[0] += __uint_as_float(v.x << 16);
    acc[1] += __uint_as_float(v.x & 0xffff0000u);
    acc[2] += __uint_as_float(v.y << 16);
    acc[3] += __uint_as_float(v.y & 0xffff0000u);
    acc[4] += __uint_as_float(v.z << 16);
    acc[5] += __uint_as_float(v.z & 0xffff0000u);
    acc[6] += __uint_as_float(v.w << 16);
    acc[7] += __uint_as_float(v.w & 0xffff0000u);
}

__global__ __launch_bounds__(256) void agg_kernel(
    const ushort* __restrict__ hb, ushort* __restrict__ tb,
    const int* __restrict__ row_ptr, const int* __restrict__ col_idx, int n)
{
    const uint4* __restrict__ hb4 = (const uint4*)hb;   // row = 8 uint4
    const int lane = threadIdx.x & 63;
    const int g = lane >> 3;     // node slot 0..7 within wave
    const int q = lane & 7;      // 16B chunk 0..7 within row
    const int wave = (blockIdx.x * blockDim.x + threadIdx.x) >> 6;
    const int i = wave * 8 + g;
    if (i >= n) return;
    const int rp0 = row_ptr[i];
    const int deg = row_ptr[i + 1] - rp0;

    float acc[8];
    {   // self term (eps = 0) — safe in init: no cross-lane reduction follows
        uint4 v = hb4[(size_t)i * 8 + q];
        acc[0] = __uint_as_float(v.x << 16);
        acc[1] = __uint_as_float(v.x & 0xffff0000u);
        acc[2] = __uint_as_float(v.y << 16);
        acc[3] = __uint_as_float(v.y & 0xffff0000u);
        acc[4] = __uint_as_float(v.z << 16);
        acc[5] = __uint_as_float(v.z & 0xffff0000u);
        acc[6] = __uint_as_float(v.w << 16);
        acc[7] = __uint_as_float(v.w & 0xffff0000u);
    }

    int e = 0;
    for (; e + 4 <= deg; e += 4) {   // 4 gathers in flight per group
        int i0 = col_idx[rp0 + e];
        int i1 = col_idx[rp0 + e + 1];
        int i2 = col_idx[rp0 + e + 2];
        int i3 = col_idx[rp0 + e + 3];
        uint4 v0 = hb4[(size_t)i0 * 8 + q];
        uint4 v1 = hb4[(size_t)i1 * 8 + q];
        uint4 v2 = hb4[(size_t)i2 * 8 + q];
        uint4 v3 = hb4[(size_t)i3 * 8 + q];
        add_unpack(acc, v0);
        add_unpack(acc, v1);
        add_unpack(acc, v2);
        add_unpack(acc, v3);
    }
    for (; e < deg; ++e) {
        int ix = col_idx[rp0 + e];
        uint4 v = hb4[(size_t)ix * 8 + q];
        add_unpack(acc, v);
    }

    uint4 o;   // pack 8 fp32 -> 8 bf16 (dims q*8 .. q*8+7)
    o.x = f2bf(acc[0]) | (f2bf(acc[1]) << 16);
    o.y = f2bf(acc[2]) | (f2bf(acc[3]) << 16);
    o.z = f2bf(acc[4]) | (f2bf(acc[5]) << 16);
    o.w = f2bf(acc[6]) | (f2bf(acc[7]) << 16);
    ((uint4*)tb)[(size_t)i * 8 + q] = o;
}

// ---------------- MLP via MFMA: hb = bf16(relu(relu(BN(t@W1+b1))@W2+b2)) ---------
// One wave per 16-node tile. GEMM1 transposed (A=W1^T frags, B=t frags straight
// from global); epilogue1 in-register (lane owns node n15, 4 consecutive cols per
// quad) -> 4x ds_write_b64 into padded LDS tile; GEMM2 standard (A=U frags via
// 2x ds_read_b128, B=W2 frags); bias+relu; b16 stores.

__global__ __launch_bounds__(256) void mlp_kernel(
    const ushort* __restrict__ tb, ushort* __restrict__ hb,
    const uint4* __restrict__ Wp,   // layer frags: [0..7]=W1^T, [8..15]=W2
    const float* __restrict__ b1, const float* __restrict__ gamma,
    const float* __restrict__ beta, const float* __restrict__ rmean,
    const float* __restrict__ rvar, const float* __restrict__ b2, int ntiles)
{
    __shared__ __align__(16) ushort U[4][16][72];   // stride 72 breaks pow-2 banks
    const int lane = threadIdx.x & 63;
    const int wid  = threadIdx.x >> 6;
    const int n15  = lane & 15, quad = lane >> 4;

    short8 w1f[8], w2f[8];
    const short8* Wp8 = (const short8*)Wp;
#pragma unroll
    for (int f = 0; f < 8; ++f) {
        w1f[f] = Wp8[f * 64 + lane];
        w2f[f] = Wp8[(8 + f) * 64 + lane];
    }
    // epilogue1 constants: lane's GEMM1 output cols j = mt*16 + quad*4 + r
    f32x4 sc[4], sh[4];
#pragma unroll
    for (int mt = 0; mt < 4; ++mt) {
        const int j0 = mt * 16 + quad * 4;
#pragma unroll
        for (int r = 0; r < 4; ++r) {
            float s = gamma[j0 + r] * rsqrtf(rvar[j0 + r] + 1e-5f);
            sc[mt][r] = s;
            sh[mt][r] = (b1[j0 + r] - rmean[j0 + r]) * s + beta[j0 + r];
        }
    }
    float bb2[4];
#pragma unroll
    for (int tc = 0; tc < 4; ++tc) bb2[tc] = b2[tc * 16 + n15];

    const int wave = blockIdx.x * 4 + wid;
    const int nwaves = gridDim.x * 4;
    for (int tile = wave; tile < ntiles; tile += nwaves) {
        const int nb = tile * 16;
        // B-frags of t^T == A-frag layout of t == direct 16B row loads
        const short8* trow = (const short8*)(tb + (size_t)(nb + n15) * 64);
        short8 t0 = trow[quad];        // k = 0..31 half
        short8 t1 = trow[4 + quad];    // k = 32..63 half

        f32x4 c1[4];
#pragma unroll
        for (int mt = 0; mt < 4; ++mt) {
            c1[mt] = (f32x4){0.f, 0.f, 0.f, 0.f};
            c1[mt] = __builtin_amdgcn_mfma_f32_16x16x32_bf16(w1f[mt * 2 + 0], t0, c1[mt], 0, 0, 0);
            c1[mt] = __builtin_amdgcn_mfma_f32_16x16x32_bf16(w1f[mt * 2 + 1], t1, c1[mt], 0, 0, 0);
        }
        // BN + ReLU; lane holds node n15, cols mt*16+quad*4 .. +3 (consecutive)
#pragma unroll
        for (int mt = 0; mt < 4; ++mt) {
            float u0 = fmaxf(c1[mt][0] * sc[mt][0] + sh[mt][0], 0.f);
            float u1 = fmaxf(c1[mt][1] * sc[mt][1] + sh[mt][1], 0.f);
            float u2 = fmaxf(c1[mt][2] * sc[mt][2] + sh[mt][2], 0.f);
            float u3 = fmaxf(c1[mt][3] * sc[mt][3] + sh[mt][3], 0.f);
            uint2 pk;
            pk.x = f2bf(u0) | (f2bf(u1) << 16);
            pk.y = f2bf(u2) | (f2bf(u3) << 16);
            *(uint2*)&U[wid][n15][mt * 16 + quad * 4] = pk;
        }
        __threadfence_block();   // drain LDS writes (per-wave tile, in-order DS)
        short8 u0 = *(const short8*)&U[wid][n15][quad * 8];        // A-frag k 0..31
        short8 u1 = *(const short8*)&U[wid][n15][32 + quad * 8];   // A-frag k 32..63

        f32x4 c2[4];
#pragma unroll
        for (int tc = 0; tc < 4; ++tc) {
            c2[tc] = (f32x4){0.f, 0.f, 0.f, 0.f};
            c2[tc] = __builtin_amdgcn_mfma_f32_16x16x32_bf16(u0, w2f[tc * 2 + 0], c2[tc], 0, 0, 0);
            c2[tc] = __builtin_amdgcn_mfma_f32_16x16x32_bf16(u1, w2f[tc * 2 + 1], c2[tc], 0, 0, 0);
        }
        // bias + ReLU; lane holds node quad*4+r, col tc*16+n15
#pragma unroll
        for (int tc = 0; tc < 4; ++tc) {
#pragma unroll
            for (int r = 0; r < 4; ++r) {
                float v = fmaxf(c2[tc][r] + bb2[tc], 0.f);
                hb[(size_t)(nb + quad * 4 + r) * 64 + tc * 16 + n15] = (ushort)f2bf(v);
            }
        }
    }
}

// ---------------- global_add_pool (batch sorted -> run-length + atomics) --------

__global__ void pool_kernel(const ushort* __restrict__ hb, const int* __restrict__ batch,
                            float* __restrict__ pooled, int n) {
    const int lane = threadIdx.x & 63;
    const int wid  = threadIdx.x >> 6;
    const int wave = blockIdx.x * 4 + wid;
    const int nwaves = gridDim.x * 4;
    const int per = (n + nwaves - 1) / nwaves;
    const int a = wave * per;
    const int b = min(a + per, n);
    if (a >= b) return;
    int cur = batch[a];
    float sum = 0.0f;
    for (int i = a; i < b; ++i) {
        int g = batch[i];
        if (g != cur) {
            atomicAdd(&pooled[cur * DIM + lane], sum);
            sum = 0.0f;
            cur = g;
        }
        sum += __uint_as_float(((uint)hb[(size_t)i * DIM + lane]) << 16);
    }
    atomicAdd(&pooled[cur * DIM + lane], sum);
}

// ---------------- head: relu(pooled@lin1+b1) @ lin2 + b2 ----------------

__global__ void head_kernel(const float* __restrict__ pooled,
                            const float* __restrict__ w1, const float* __restrict__ b1,
                            const float* __restrict__ w2, const float* __restrict__ b2,
                            float* __restrict__ out) {
    const int g = blockIdx.x;
    const int lane = threadIdx.x;  // 64 threads = 1 wave
    __shared__ float pl[DIM];
    __shared__ float y1l[DIM];
    pl[lane] = pooled[g * DIM + lane];
    __syncthreads();
    float y = b1[lane];
#pragma unroll
    for (int d = 0; d < DIM; ++d) y += pl[d] * w1[d * DIM + lane];
    y1l[lane] = fmaxf(y, 0.0f);
    __syncthreads();
    if (lane < OUT_DIM) {
        float y2 = b2[lane];
#pragma unroll
        for (int d = 0; d < DIM; ++d) y2 += y1l[d] * w2[d * OUT_DIM + lane];
        out[g * OUT_DIM + lane] = y2;
    }
}

// ---------------- launch ----------------

extern "C" void kernel_launch(void* const* d_in, const int* in_sizes, int n_in,
                              void* d_out, int out_size, void* d_ws, size_t ws_size,
                              hipStream_t stream) {
    const float* x     = (const float*)d_in[0];
    const int*   eidx  = (const int*)  d_in[1];   // [2, N_EDGES]: src row then dst row
    const int*   batch = (const int*)  d_in[2];
    const float* W1    = (const float*)d_in[3];
    const float* b1    = (const float*)d_in[4];
    const float* gamma = (const float*)d_in[5];
    const float* beta  = (const float*)d_in[6];
    const float* rmean = (const float*)d_in[7];
    const float* rvar  = (const float*)d_in[8];
    const float* W2    = (const float*)d_in[9];
    const float* b2    = (const float*)d_in[10];
    const float* l1w   = (const float*)d_in[11];
    const float* l1b   = (const float*)d_in[12];
    const float* l2w   = (const float*)d_in[13];
    const float* l2b   = (const float*)d_in[14];
    float* out = (float*)d_out;

    // workspace layout (padded, 16B-aligned pieces)
    int* counts    = (int*)d_ws;              // 100000
    int* fillc     = counts    + 100352;      // 100000
    int* row_ptr   = fillc     + 100352;      // 100001
    int* blockSums = row_ptr   + 100352;      // 196
    int* blockOffs = blockSums + 256;         // 196
    int* col_idx   = blockOffs + 256;         // 1600000
    uint4* Wp      = (uint4*)(col_idx + 1600000 + 192);        // 10*8*64 uint4 = 80KB
    ushort* tb     = (ushort*)(Wp + 10 * 8 * 64);              // 100000*64 bf16 (12.8MB)
    ushort* hb     = tb + (size_t)N_NODES * DIM;               // 100000*64 bf16 (12.8MB)
    float* pooled  = (float*)(hb + (size_t)N_NODES * DIM);     // 128*64 fp32

    const int* srcp = eidx;
    const int* dstp = eidx + N_EDGES;

    hipMemsetAsync(counts, 0, N_NODES * sizeof(int), stream);
    hipMemsetAsync(pooled, 0, N_GRAPHS * DIM * sizeof(float), stream);

    cvt_kernel<<<(N_NODES * DIM / 4 + 255) / 256, 256, 0, stream>>>(x, hb, N_NODES * DIM / 4);
    repack_kernel<<<1, 640, 0, stream>>>(W1, W2, Wp);
    count_kernel<<<1024, 256, 0, stream>>>(dstp, counts, N_EDGES);
    scanA_kernel<<<SCAN_NB, 256, 0, stream>>>(counts, blockSums, N_NODES);
    scanB_kernel<<<1, 256, 0, stream>>>(blockSums, blockOffs, row_ptr);
    scanC_kernel<<<SCAN_NB, 256, 0, stream>>>(counts, blockOffs, row_ptr, fillc, N_NODES);
    fill_kernel<<<1024, 256, 0, stream>>>(srcp, dstp, fillc, col_idx, N_EDGES);

    const int agg_blocks = ((N_NODES + 7) / 8 * 64 + 255) / 256;  // 8 nodes per wave
    const int ntiles = N_NODES / 16;                               // 6250 exact

    for (int l = 0; l < 5; ++l) {
        agg_kernel<<<agg_blocks, 256, 0, stream>>>(hb, tb, row_ptr, col_idx, N_NODES);
        mlp_kernel<<<512, 256, 0, stream>>>(
            tb, hb, Wp + (size_t)l * 2 * 8 * 64,
            b1 + (size_t)l * DIM, gamma + (size_t)l * DIM, beta + (size_t)l * DIM,
            rmean + (size_t)l * DIM, rvar + (size_t)l * DIM, b2 + (size_t)l * DIM, ntiles);
    }
    pool_kernel<<<2048, 256, 0, stream>>>(hb, batch, pooled, N_NODES);
    head_kernel<<<N_GRAPHS, 64, 0, stream>>>(pooled, l1w, l1b, l2w, l2b, out);
}

// Round 8
// 483.836 us; speedup vs baseline: 3.7615x; 1.0031x over previous
//
#include <hip/hip_runtime.h>

#define N_NODES  100000
#define N_EDGES  1600000
#define DIM      64
#define N_GRAPHS 128
#define OUT_DIM  10
#define SCAN_NB    196
#define SCAN_CHUNK 512   // 196*512 = 100352 >= N_NODES; 2 elems/thread @256 threads

typedef unsigned int uint;
typedef unsigned short ushort;
typedef __attribute__((ext_vector_type(8))) short short8;   // 8 bf16 = 4 VGPRs
typedef __attribute__((ext_vector_type(4))) float f32x4;

__device__ __forceinline__ uint f2bf(float x) {   // fp32 -> bf16 bits (RNE)
    uint b = __float_as_uint(x);
    b += 0x7fffu + ((b >> 16) & 1u);
    return b >> 16;
}

// ---------------- CSR build (bucket edges by dst) ----------------
// XCD-partitioned: block handles dst range p = blockIdx & 7 (blockIdx%8 maps
// round-robin to the 8 XCDs). All atomics/stores for a given fillc/col_idx
// range then come from ONE XCD -> lines merge in its L2 instead of bouncing
// through HBM between non-coherent per-XCD L2s (R7: 90MB WRITE from bouncing).

__global__ void count_kernel(const int* __restrict__ dst, int* __restrict__ counts, int n) {
    const int pass = blockIdx.x & 7;
    if (pass >= 7) return;                       // dst>>14 is 0..6
    const int nb = gridDim.x >> 3;               // blocks per pass
    const int bid = blockIdx.x >> 3;
    int i = bid * blockDim.x + threadIdx.x;
    const int stride = nb * blockDim.x;
    for (; i < n; i += stride) {
        int d = dst[i];
        if ((d >> 14) == pass) atomicAdd(&counts[d], 1);
    }
}

__global__ void scanA_kernel(const int* __restrict__ counts, int* __restrict__ blockSums, int n) {
    __shared__ int red[256];
    const int b = blockIdx.x, t = threadIdx.x;
    const int base = b * SCAN_CHUNK + t * 2;
    int s = 0;
    if (base < n)     s += counts[base];
    if (base + 1 < n) s += counts[base + 1];
    red[t] = s;
    __syncthreads();
    for (int off = 128; off > 0; off >>= 1) {
        if (t < off) red[t] += red[t + off];
        __syncthreads();
    }
    if (t == 0) blockSums[b] = red[0];
}

__global__ void scanB_kernel(const int* __restrict__ blockSums, int* __restrict__ blockOffs,
                             int* __restrict__ row_ptr) {
    __shared__ int sc[256];
    const int t = threadIdx.x;
    const int v = (t < SCAN_NB) ? blockSums[t] : 0;
    sc[t] = v;
    __syncthreads();
    for (int off = 1; off < 256; off <<= 1) {
        int u = (t >= off) ? sc[t - off] : 0;
        __syncthreads();
        sc[t] += u;
        __syncthreads();
    }
    if (t < SCAN_NB) blockOffs[t] = sc[t] - v;   // exclusive block offset
    if (t == 255) row_ptr[N_NODES] = sc[255];    // total == N_EDGES
}

// also initializes fillc = row_ptr so fill_kernel needs only ONE random access
__global__ void scanC_kernel(const int* __restrict__ counts, const int* __restrict__ blockOffs,
                             int* __restrict__ row_ptr, int* __restrict__ fillc, int n) {
    __shared__ int sc[256];
    const int b = blockIdx.x, t = threadIdx.x;
    const int base = b * SCAN_CHUNK + t * 2;
    const int c0 = (base < n) ? counts[base] : 0;
    const int c1 = (base + 1 < n) ? counts[base + 1] : 0;
    const int s = c0 + c1;
    sc[t] = s;
    __syncthreads();
    for (int off = 1; off < 256; off <<= 1) {
        int u = (t >= off) ? sc[t - off] : 0;
        __syncthreads();
        sc[t] += u;
        __syncthreads();
    }
    const int pre = blockOffs[b] + sc[t] - s;    // exclusive prefix for base
    if (base < n)     { row_ptr[base]     = pre;      fillc[base]     = pre; }
    if (base + 1 < n) { row_ptr[base + 1] = pre + c0; fillc[base + 1] = pre + c0; }
}

__global__ void fill_kernel(const int* __restrict__ src, const int* __restrict__ dst,
                            int* __restrict__ fillc, int* __restrict__ col_idx, int n) {
    const int pass = blockIdx.x & 7;
    if (pass >= 7) return;
    const int nb = gridDim.x >> 3;
    const int bid = blockIdx.x >> 3;
    int i = bid * blockDim.x + threadIdx.x;
    const int stride = nb * blockDim.x;
    for (; i < n; i += stride) {
        int d = dst[i];
        if ((d >> 14) == pass) {
            int pos = atomicAdd(&fillc[d], 1);
            col_idx[pos] = src[i];
        }
    }
}

// ---------------- x (fp32) -> bf16 rows ----------------

__global__ void cvt_kernel(const float* __restrict__ x, ushort* __restrict__ xb, int n4) {
    int idx = blockIdx.x * blockDim.x + threadIdx.x;
    if (idx >= n4) return;
    float4 v = ((const float4*)x)[idx];
    uint2 o;
    o.x = f2bf(v.x) | (f2bf(v.y) << 16);
    o.y = f2bf(v.z) | (f2bf(v.w) << 16);
    ((uint2*)xb)[idx] = o;
}

// ---------------- Weight repack: MFMA fragment layouts, once per launch ----------

__global__ void repack_kernel(const float* __restrict__ W1, const float* __restrict__ W2,
                              uint4* __restrict__ Wp) {
    const int wave = (blockIdx.x * blockDim.x + threadIdx.x) >> 6;
    if (wave >= 10) return;
    const int layer = wave >> 1;
    const float* W = (wave & 1) ? (W2 + layer * 4096) : (W1 + layer * 4096);
    const int lane = threadIdx.x & 63;
    const int n15 = lane & 15, quad = lane >> 4;
#pragma unroll
    for (int f = 0; f < 8; ++f) {
        const int outer = f >> 1, h = f & 1;
        uint p[4];
#pragma unroll
        for (int pj = 0; pj < 4; ++pj) {
            const int k0 = h * 32 + quad * 8 + 2 * pj;
            uint lo = f2bf(W[k0 * 64 + outer * 16 + n15]);
            uint hi = f2bf(W[(k0 + 1) * 64 + outer * 16 + n15]);
            p[pj] = lo | (hi << 16);
        }
        Wp[(wave * 8 + f) * 64 + lane] = make_uint4(p[0], p[1], p[2], p[3]);
    }
}

// ---------------- Aggregation: tb[i] = hb[i] + sum_{j in N(i)} hb[j] -> bf16 ------
// GROUP-PER-NODE: 8 lanes/node, 8 nodes/wave, 4 dwordx4 gathers in flight.

__device__ __forceinline__ void add_unpack(float acc[8], uint4 v) {
    acc[0] += __uint_as_float(v.x << 16);
    acc[1] += __uint_as_float(v.x & 0xffff0000u);
    acc[2] += __uint_as_float(v.y << 16);
    acc[3] += __uint_as_float(v.y & 0xffff0000u);
    acc[4] += __uint_as_float(v.z << 16);
    acc[5] += __uint_as_float(v.z & 0xffff0000u);
    acc[6] += __uint_as_float(v.w << 16);
    acc[7] += __uint_as_float(v.w & 0xffff0000u);
}

__global__ __launch_bounds__(256) void agg_kernel(
    const ushort* __restrict__ hb, ushort* __restrict__ tb,
    const int* __restrict__ row_ptr, const int* __restrict__ col_idx, int n)
{
    const uint4* __restrict__ hb4 = (const uint4*)hb;   // row = 8 uint4
    const int lane = threadIdx.x & 63;
    const int g = lane >> 3;     // node slot 0..7 within wave
    const int q = lane & 7;      // 16B chunk 0..7 within row
    const int wave = (blockIdx.x * blockDim.x + threadIdx.x) >> 6;
    const int i = wave * 8 + g;
    if (i >= n) return;
    const int rp0 = row_ptr[i];
    const int deg = row_ptr[i + 1] - rp0;

    float acc[8];
    {   // self term (eps = 0) — safe in init: no cross-lane reduction follows
        uint4 v = hb4[(size_t)i * 8 + q];
        acc[0] = __uint_as_float(v.x << 16);
        acc[1] = __uint_as_float(v.x & 0xffff0000u);
        acc[2] = __uint_as_float(v.y << 16);
        acc[3] = __uint_as_float(v.y & 0xffff0000u);
        acc[4] = __uint_as_float(v.z << 16);
        acc[5] = __uint_as_float(v.z & 0xffff0000u);
        acc[6] = __uint_as_float(v.w << 16);
        acc[7] = __uint_as_float(v.w & 0xffff0000u);
    }

    int e = 0;
    for (; e + 4 <= deg; e += 4) {   // 4 gathers in flight per group
        int i0 = col_idx[rp0 + e];
        int i1 = col_idx[rp0 + e + 1];
        int i2 = col_idx[rp0 + e + 2];
        int i3 = col_idx[rp0 + e + 3];
        uint4 v0 = hb4[(size_t)i0 * 8 + q];
        uint4 v1 = hb4[(size_t)i1 * 8 + q];
        uint4 v2 = hb4[(size_t)i2 * 8 + q];
        uint4 v3 = hb4[(size_t)i3 * 8 + q];
        add_unpack(acc, v0);
        add_unpack(acc, v1);
        add_unpack(acc, v2);
        add_unpack(acc, v3);
    }
    for (; e < deg; ++e) {
        int ix = col_idx[rp0 + e];
        uint4 v = hb4[(size_t)ix * 8 + q];
        add_unpack(acc, v);
    }

    uint4 o;   // pack 8 fp32 -> 8 bf16 (dims q*8 .. q*8+7)
    o.x = f2bf(acc[0]) | (f2bf(acc[1]) << 16);
    o.y = f2bf(acc[2]) | (f2bf(acc[3]) << 16);
    o.z = f2bf(acc[4]) | (f2bf(acc[5]) << 16);
    o.w = f2bf(acc[6]) | (f2bf(acc[7]) << 16);
    ((uint4*)tb)[(size_t)i * 8 + q] = o;
}

// ---------------- MLP via MFMA (R7 structure, unchanged) ----------------

__global__ __launch_bounds__(256) void mlp_kernel(
    const ushort* __restrict__ tb, ushort* __restrict__ hb,
    const uint4* __restrict__ Wp,   // layer frags: [0..7]=W1^T, [8..15]=W2
    const float* __restrict__ b1, const float* __restrict__ gamma,
    const float* __restrict__ beta, const float* __restrict__ rmean,
    const float* __restrict__ rvar, const float* __restrict__ b2, int ntiles)
{
    __shared__ __align__(16) ushort U[4][16][72];   // stride 72 breaks pow-2 banks
    const int lane = threadIdx.x & 63;
    const int wid  = threadIdx.x >> 6;
    const int n15  = lane & 15, quad = lane >> 4;

    short8 w1f[8], w2f[8];
    const short8* Wp8 = (const short8*)Wp;
#pragma unroll
    for (int f = 0; f < 8; ++f) {
        w1f[f] = Wp8[f * 64 + lane];
        w2f[f] = Wp8[(8 + f) * 64 + lane];
    }
    f32x4 sc[4], sh[4];
#pragma unroll
    for (int mt = 0; mt < 4; ++mt) {
        const int j0 = mt * 16 + quad * 4;
#pragma unroll
        for (int r = 0; r < 4; ++r) {
            float s = gamma[j0 + r] * rsqrtf(rvar[j0 + r] + 1e-5f);
            sc[mt][r] = s;
            sh[mt][r] = (b1[j0 + r] - rmean[j0 + r]) * s + beta[j0 + r];
        }
    }
    float bb2[4];
#pragma unroll
    for (int tc = 0; tc < 4; ++tc) bb2[tc] = b2[tc * 16 + n15];

    const int wave = blockIdx.x * 4 + wid;
    const int nwaves = gridDim.x * 4;
    for (int tile = wave; tile < ntiles; tile += nwaves) {
        const int nb = tile * 16;
        const short8* trow = (const short8*)(tb + (size_t)(nb + n15) * 64);
        short8 t0 = trow[quad];        // k = 0..31 half
        short8 t1 = trow[4 + quad];    // k = 32..63 half

        f32x4 c1[4];
#pragma unroll
        for (int mt = 0; mt < 4; ++mt) {
            c1[mt] = (f32x4){0.f, 0.f, 0.f, 0.f};
            c1[mt] = __builtin_amdgcn_mfma_f32_16x16x32_bf16(w1f[mt * 2 + 0], t0, c1[mt], 0, 0, 0);
            c1[mt] = __builtin_amdgcn_mfma_f32_16x16x32_bf16(w1f[mt * 2 + 1], t1, c1[mt], 0, 0, 0);
        }
#pragma unroll
        for (int mt = 0; mt < 4; ++mt) {
            float u0 = fmaxf(c1[mt][0] * sc[mt][0] + sh[mt][0], 0.f);
            float u1 = fmaxf(c1[mt][1] * sc[mt][1] + sh[mt][1], 0.f);
            float u2 = fmaxf(c1[mt][2] * sc[mt][2] + sh[mt][2], 0.f);
            float u3 = fmaxf(c1[mt][3] * sc[mt][3] + sh[mt][3], 0.f);
            uint2 pk;
            pk.x = f2bf(u0) | (f2bf(u1) << 16);
            pk.y = f2bf(u2) | (f2bf(u3) << 16);
            *(uint2*)&U[wid][n15][mt * 16 + quad * 4] = pk;
        }
        __threadfence_block();
        short8 u0 = *(const short8*)&U[wid][n15][quad * 8];
        short8 u1 = *(const short8*)&U[wid][n15][32 + quad * 8];

        f32x4 c2[4];
#pragma unroll
        for (int tc = 0; tc < 4; ++tc) {
            c2[tc] = (f32x4){0.f, 0.f, 0.f, 0.f};
            c2[tc] = __builtin_amdgcn_mfma_f32_16x16x32_bf16(u0, w2f[tc * 2 + 0], c2[tc], 0, 0, 0);
            c2[tc] = __builtin_amdgcn_mfma_f32_16x16x32_bf16(u1, w2f[tc * 2 + 1], c2[tc], 0, 0, 0);
        }
#pragma unroll
        for (int tc = 0; tc < 4; ++tc) {
#pragma unroll
            for (int r = 0; r < 4; ++r) {
                float v = fmaxf(c2[tc][r] + bb2[tc], 0.f);
                hb[(size_t)(nb + quad * 4 + r) * 64 + tc * 16 + n15] = (ushort)f2bf(v);
            }
        }
    }
}

// ---------------- global_add_pool (batch sorted -> run-length + atomics) --------

__global__ void pool_kernel(const ushort* __restrict__ hb, const int* __restrict__ batch,
                            float* __restrict__ pooled, int n) {
    const int lane = threadIdx.x & 63;
    const int wid  = threadIdx.x >> 6;
    const int wave = blockIdx.x * 4 + wid;
    const int nwaves = gridDim.x * 4;
    const int per = (n + nwaves - 1) / nwaves;
    const int a = wave * per;
    const int b = min(a + per, n);
    if (a >= b) return;
    int cur = batch[a];
    float sum = 0.0f;
    for (int i = a; i < b; ++i) {
        int g = batch[i];
        if (g != cur) {
            atomicAdd(&pooled[cur * DIM + lane], sum);
            sum = 0.0f;
            cur = g;
        }
        sum += __uint_as_float(((uint)hb[(size_t)i * DIM + lane]) << 16);
    }
    atomicAdd(&pooled[cur * DIM + lane], sum);
}

// ---------------- head: relu(pooled@lin1+b1) @ lin2 + b2 ----------------

__global__ void head_kernel(const float* __restrict__ pooled,
                            const float* __restrict__ w1, const float* __restrict__ b1,
                            const float* __restrict__ w2, const float* __restrict__ b2,
                            float* __restrict__ out) {
    const int g = blockIdx.x;
    const int lane = threadIdx.x;  // 64 threads = 1 wave
    __shared__ float pl[DIM];
    __shared__ float y1l[DIM];
    pl[lane] = pooled[g * DIM + lane];
    __syncthreads();
    float y = b1[lane];
#pragma unroll
    for (int d = 0; d < DIM; ++d) y += pl[d] * w1[d * DIM + lane];
    y1l[lane] = fmaxf(y, 0.0f);
    __syncthreads();
    if (lane < OUT_DIM) {
        float y2 = b2[lane];
#pragma unroll
        for (int d = 0; d < DIM; ++d) y2 += y1l[d] * w2[d * OUT_DIM + lane];
        out[g * OUT_DIM + lane] = y2;
    }
}

// ---------------- launch ----------------

extern "C" void kernel_launch(void* const* d_in, const int* in_sizes, int n_in,
                              void* d_out, int out_size, void* d_ws, size_t ws_size,
                              hipStream_t stream) {
    const float* x     = (const float*)d_in[0];
    const int*   eidx  = (const int*)  d_in[1];   // [2, N_EDGES]: src row then dst row
    const int*   batch = (const int*)  d_in[2];
    const float* W1    = (const float*)d_in[3];
    const float* b1    = (const float*)d_in[4];
    const float* gamma = (const float*)d_in[5];
    const float* beta  = (const float*)d_in[6];
    const float* rmean = (const float*)d_in[7];
    const float* rvar  = (const float*)d_in[8];
    const float* W2    = (const float*)d_in[9];
    const float* b2    = (const float*)d_in[10];
    const float* l1w   = (const float*)d_in[11];
    const float* l1b   = (const float*)d_in[12];
    const float* l2w   = (const float*)d_in[13];
    const float* l2b   = (const float*)d_in[14];
    float* out = (float*)d_out;

    // workspace layout (padded, 16B-aligned pieces)
    int* counts    = (int*)d_ws;              // 100000
    int* fillc     = counts    + 100352;      // 100000
    int* row_ptr   = fillc     + 100352;      // 100001
    int* blockSums = row_ptr   + 100352;      // 196
    int* blockOffs = blockSums + 256;         // 196
    int* col_idx   = blockOffs + 256;         // 1600000
    uint4* Wp      = (uint4*)(col_idx + 1600000 + 192);        // 10*8*64 uint4 = 80KB
    ushort* tb     = (ushort*)(Wp + 10 * 8 * 64);              // 100000*64 bf16 (12.8MB)
    ushort* hb     = tb + (size_t)N_NODES * DIM;               // 100000*64 bf16 (12.8MB)
    float* pooled  = (float*)(hb + (size_t)N_NODES * DIM);     // 128*64 fp32

    const int* srcp = eidx;
    const int* dstp = eidx + N_EDGES;

    hipMemsetAsync(counts, 0, N_NODES * sizeof(int), stream);
    hipMemsetAsync(pooled, 0, N_GRAPHS * DIM * sizeof(float), stream);

    cvt_kernel<<<(N_NODES * DIM / 4 + 255) / 256, 256, 0, stream>>>(x, hb, N_NODES * DIM / 4);
    repack_kernel<<<1, 640, 0, stream>>>(W1, W2, Wp);
    count_kernel<<<2048, 256, 0, stream>>>(dstp, counts, N_EDGES);
    scanA_kernel<<<SCAN_NB, 256, 0, stream>>>(counts, blockSums, N_NODES);
    scanB_kernel<<<1, 256, 0, stream>>>(blockSums, blockOffs, row_ptr);
    scanC_kernel<<<SCAN_NB, 256, 0, stream>>>(counts, blockOffs, row_ptr, fillc, N_NODES);
    fill_kernel<<<2048, 256, 0, stream>>>(srcp, dstp, fillc, col_idx, N_EDGES);

    const int agg_blocks = ((N_NODES + 7) / 8 * 64 + 255) / 256;  // 8 nodes per wave
    const int ntiles = N_NODES / 16;                               // 6250 exact

    for (int l = 0; l < 5; ++l) {
        agg_kernel<<<agg_blocks, 256, 0, stream>>>(hb, tb, row_ptr, col_idx, N_NODES);
        mlp_kernel<<<512, 256, 0, stream>>>(
            tb, hb, Wp + (size_t)l * 2 * 8 * 64,
            b1 + (size_t)l * DIM, gamma + (size_t)l * DIM, beta + (size_t)l * DIM,
            rmean + (size_t)l * DIM, rvar + (size_t)l * DIM, b2 + (size_t)l * DIM, ntiles);
    }
    pool_kernel<<<2048, 256, 0, stream>>>(hb, batch, pooled, N_NODES);
    head_kernel<<<N_GRAPHS, 64, 0, stream>>>(pooled, l1w, l1b, l2w, l2b, out);
}